// Round 6
// baseline (5698.883 us; speedup 1.0000x reference)
//
#include <hip/hip_runtime.h>
#include <hip/hip_bf16.h>

#define T_TOK 4096
#define H_DIM 4096
#define I_DIM 2048
#define N_EXP 8
#define TOPK  2
#define NPAIR (T_TOK*TOPK)          // 8192
#define BM    128                   // fallback gemm2 M-tile
#define BK    32
#define MAXT  (NPAIR/BM + N_EXP)    // 72
#define BM1   256
#define BN1   128
#define BK1   64
#define MAXT1 (NPAIR/BM1 + N_EXP)   // 40

// ---- tiled-workspace offsets (bytes) ----
#define HT_OFF   ((size_t)1 << 20)
#define W0_OFF   ((size_t)45 << 20)                 // > 1MB + 40MB Ht
#define W1_OFF   (W0_OFF + 134217728ull)
#define AT_OFF   (W1_OFF + 134217728ull)
#define NEED_NEW (AT_OFF + 83886080ull)             // ~381 MB
// Wot overlays W0 (Wi0b dead after gemm1b)

typedef __attribute__((ext_vector_type(8))) short  bf16x8;
typedef __attribute__((ext_vector_type(4))) float  f32x4v;

__device__ __forceinline__ short f2bf(float f) {
    __hip_bfloat16 h = __float2bfloat16(f);
    return __builtin_bit_cast(short, h);
}

__device__ __forceinline__ bf16x8 pack8(f32x4v a, f32x4v b) {
    bf16x8 r;
    r[0]=f2bf(a[0]); r[1]=f2bf(a[1]); r[2]=f2bf(a[2]); r[3]=f2bf(a[3]);
    r[4]=f2bf(b[0]); r[5]=f2bf(b[1]); r[6]=f2bf(b[2]); r[7]=f2bf(b[3]);
    return r;
}

__device__ __forceinline__ void load_lds16(const short* g, short* l) {
    __builtin_amdgcn_global_load_lds(
        (const __attribute__((address_space(1))) void*)g,
        (__attribute__((address_space(3))) void*)l, 16, 0, 0);
}

// ---------------- fp32 -> bf16 plain (fallback X path) ----------------
__global__ void cvt_kernel(const float* __restrict__ X, short* __restrict__ Xbf) {
    const size_t i = ((size_t)blockIdx.x * 256 + threadIdx.x) * 8;
    f32x4v a = *(const f32x4v*)(X + i);
    f32x4v b = *(const f32x4v*)(X + i + 4);
    *(bf16x8*)(Xbf + i) = pack8(a, b);
}

// ---------------- routing ----------------
__global__ void route_kernel(const int* __restrict__ ids, const float* __restrict__ wts,
                             int* __restrict__ pair_token, float* __restrict__ pair_w,
                             int* __restrict__ tile_expert, int* __restrict__ tile_row0,
                             int* __restrict__ tile_rows,
                             int* __restrict__ t1_expert, int* __restrict__ t1_row0,
                             int* __restrict__ t1_rows)
{
    __shared__ int scn[256][N_EXP];
    const int tid = threadIdx.x;
    const int PPT = NPAIR / 256;
    const int base = tid * PPT;

    int c[N_EXP], orig[N_EXP];
    #pragma unroll
    for (int e = 0; e < N_EXP; ++e) c[e] = 0;
    for (int p = 0; p < PPT; ++p) c[ids[base + p]]++;
    #pragma unroll
    for (int e = 0; e < N_EXP; ++e) { orig[e] = c[e]; scn[tid][e] = c[e]; }
    __syncthreads();

    for (int off = 1; off < 256; off <<= 1) {
        int add[N_EXP];
        #pragma unroll
        for (int e = 0; e < N_EXP; ++e) add[e] = (tid >= off) ? scn[tid - off][e] : 0;
        __syncthreads();
        #pragma unroll
        for (int e = 0; e < N_EXP; ++e) { c[e] += add[e]; scn[tid][e] = c[e]; }
        __syncthreads();
    }

    int segs[N_EXP + 1];
    {
        int run = 0;
        #pragma unroll
        for (int e = 0; e < N_EXP; ++e) { segs[e] = run; run += scn[255][e]; }
        segs[N_EXP] = run;
    }
    int pos[N_EXP];
    #pragma unroll
    for (int e = 0; e < N_EXP; ++e) pos[e] = segs[e] + c[e] - orig[e];

    for (int p = 0; p < PPT; ++p) {
        int pp = base + p;
        int e = ids[pp];
        int q = pos[e]++;
        pair_token[q] = pp / TOPK;
        pair_w[q]     = wts[pp];
    }

    if (tid == 0) {
        int t = 0;
        for (int e = 0; e < N_EXP; ++e) {
            int s = segs[e], en = segs[e + 1];
            for (int r = s; r < en; r += BM) {
                tile_expert[t] = e; tile_row0[t] = r; tile_rows[t] = min(BM, en - r); ++t;
            }
        }
        for (; t < MAXT; ++t) { tile_expert[t] = 0; tile_row0[t] = 0; tile_rows[t] = 0; }

        t = 0;
        for (int e = 0; e < N_EXP; ++e) {
            int s = segs[e], en = segs[e + 1];
            for (int r = s; r < en; r += BM1) {
                t1_expert[t] = e; t1_row0[t] = r; t1_rows[t] = min(BM1, en - r); ++t;
            }
        }
        for (; t < MAXT1; ++t) { t1_expert[t] = 0; t1_row0[t] = 0; t1_rows[t] = 0; }
    }
}

// ---------------- prep: Wi (E,I,H) fp32 -> tiled bf16 [e][i>>7][h>>5][(h>>3)&3][i&127][h&7] ----------------
__global__ void wprep_kernel(const float* __restrict__ W, short* __restrict__ Wt) {
    const size_t gid = (size_t)blockIdx.x * 256 + threadIdx.x;
    const size_t rowIdx = gid >> 9;          // e*2048 + i
    const int    h8     = (int)(gid & 511);
    const int    e = (int)(rowIdx >> 11);
    const int    i = (int)(rowIdx & 2047);

    const float* src = W + rowIdx * H_DIM + h8 * 8;
    f32x4v a = *(const f32x4v*)(src);
    f32x4v b = *(const f32x4v*)(src + 4);

    size_t dst = ((((size_t)e * 16 + (i >> 7)) * 128 + (h8 >> 2)) * 4096)
               + (size_t)(h8 & 3) * 1024 + (size_t)(i & 127) * 8;
    *(bf16x8*)(Wt + dst) = pack8(a, b);
}

// ---------------- prep: Wo (E,H,I) fp32 -> tiled bf16 [e][h>>8][i>>5][(i>>3)&3][h&255][i&7] ----------------
__global__ void woprep_kernel(const float* __restrict__ W, short* __restrict__ Wt) {
    const size_t gid = (size_t)blockIdx.x * 256 + threadIdx.x;
    const size_t rowIdx = gid >> 8;          // e*4096 + hh
    const int    i8     = (int)(gid & 255);
    const int    e  = (int)(rowIdx >> 12);
    const int    hh = (int)(rowIdx & 4095);

    const float* src = W + rowIdx * I_DIM + i8 * 8;
    f32x4v a = *(const f32x4v*)(src);
    f32x4v b = *(const f32x4v*)(src + 4);

    size_t dst = ((((size_t)e * 16 + (hh >> 8)) * 64 + (i8 >> 2)) * 8192)
               + (size_t)(i8 & 3) * 2048 + (size_t)(hh & 255) * 8;
    *(bf16x8*)(Wt + dst) = pack8(a, b);
}

// ---------------- prep: gather X rows -> A-tiles [tile][h>>5][(h>>3)&3][r][h&7] ----------------
__global__ void aprep_kernel(const float* __restrict__ X,
                             const int* __restrict__ pair_token,
                             const int* __restrict__ t1_row0, const int* __restrict__ t1_rows,
                             short* __restrict__ At) {
    const size_t gid = (size_t)blockIdx.x * 256 + threadIdx.x;
    const int r_lin = (int)(gid >> 9);       // tile*256 + r
    const int h8    = (int)(gid & 511);
    const int tile  = r_lin >> 8;
    const int r     = r_lin & 255;
    const int rows  = t1_rows[tile];
    if (rows == 0) return;
    const int tok = pair_token[t1_row0[tile] + min(r, rows - 1)];

    const float* src = X + (size_t)tok * H_DIM + h8 * 8;
    f32x4v a = *(const f32x4v*)(src);
    f32x4v b = *(const f32x4v*)(src + 4);

    size_t dst = (((size_t)tile * 128 + (h8 >> 2)) * 8192)
               + (size_t)(h8 & 3) * 2048 + (size_t)r * 8;
    *(bf16x8*)(At + dst) = pack8(a, b);
}

// ================= tiled-stream GEMMs: linear gload_lds, 2-stage ring, 2 blocks/CU =================
// LDS slots (16B each) within one 32KB stage:
//   gemm1: A [0..1023]=c*256+r, B0 [1024..1535]=c*128+r, B1 [1536..2047]=c*128+r
//   gemm2: A [0..1023]=c*256+r, B  [1024..2047]=c*256+r

__global__ __launch_bounds__(512, 4) void gemm1b_kernel(
    const short* __restrict__ At,       // [40][128][4][256][8]
    const short* __restrict__ W0t,      // [E][16][128][4][128][8]
    const short* __restrict__ W1t,
    const float* __restrict__ pair_w,
    const int* __restrict__ t1_expert, const int* __restrict__ t1_row0,
    const int* __restrict__ t1_rows,
    short* __restrict__ Ht)             // [40][64][4][256][8]
{
    const int b = blockIdx.x;
    const int l = (b & 7) * 80 + (b >> 3);
    const int tile  = l % 40;
    const int n0idx = l / 40;            // over I/128
    const int rows = t1_rows[tile];
    if (rows == 0) return;
    const int e    = t1_expert[tile];
    const int row0 = t1_row0[tile];
    const int n0   = n0idx * BN1;

    __shared__ short stg[2][16384];      // 64 KB -> 2 blocks/CU
    __shared__ float sPw[BM1];

    const int tid  = threadIdx.x;
    const int lane = tid & 63;
    const int w    = tid >> 6;
    const int wof  = w * 512;            // wave-uniform LDS short-offset base

    if (tid < BM1) sPw[tid] = (tid < rows) ? pair_w[row0 + tid] : 0.f;
    __syncthreads();

    const short* aT  = At  + (size_t)tile * 1048576 + (size_t)tid * 8;
    const short* b0T = W0t + ((size_t)e * 16 + n0idx) * 524288 + (size_t)tid * 8;
    const short* b1T = W1t + ((size_t)e * 16 + n0idx) * 524288 + (size_t)tid * 8;

    const int wr = w >> 1, wc = w & 1;
    const int frow = lane & 15, fsel = lane >> 4;

    f32x4v accg[4][4], accu[4][4];
    #pragma unroll
    for (int mf = 0; mf < 4; ++mf)
        #pragma unroll
        for (int nf = 0; nf < 4; ++nf) { accg[mf][nf] = (f32x4v)0.f; accu[mf][nf] = (f32x4v)0.f; }

#define STAGE1(s, kt) do { \
        short* st_ = &stg[s][0] + wof; \
        const size_t ko_ = (size_t)(kt); \
        load_lds16(aT  + ko_ * 8192,        st_); \
        load_lds16(aT  + ko_ * 8192 + 4096, st_ + 4096); \
        load_lds16(b0T + ko_ * 4096,        st_ + 8192); \
        load_lds16(b1T + ko_ * 4096,        st_ + 12288); \
    } while (0)

#define COMPUTE1(s) do { \
        const short* st_ = &stg[s][0]; \
        bf16x8 af[4], b0f[4], b1f[4]; \
        _Pragma("unroll") \
        for (int mf = 0; mf < 4; ++mf) \
            af[mf] = *(const bf16x8*)(st_ + (fsel * 256 + wr * 64 + mf * 16 + frow) * 8); \
        _Pragma("unroll") \
        for (int nf = 0; nf < 4; ++nf) { \
            b0f[nf] = *(const bf16x8*)(st_ + (1024 + fsel * 128 + wc * 64 + nf * 16 + frow) * 8); \
            b1f[nf] = *(const bf16x8*)(st_ + (1536 + fsel * 128 + wc * 64 + nf * 16 + frow) * 8); \
        } \
        __builtin_amdgcn_s_setprio(1); \
        _Pragma("unroll") \
        for (int nf = 0; nf < 4; ++nf) \
            _Pragma("unroll") \
            for (int mf = 0; mf < 4; ++mf) { \
                accg[mf][nf] = __builtin_amdgcn_mfma_f32_16x16x32_bf16(af[mf], b0f[nf], accg[mf][nf], 0, 0, 0); \
                accu[mf][nf] = __builtin_amdgcn_mfma_f32_16x16x32_bf16(af[mf], b1f[nf], accu[mf][nf], 0, 0, 0); \
            } \
        __builtin_amdgcn_s_setprio(0); \
    } while (0)

    STAGE1(0, 0); STAGE1(1, 1);
    asm volatile("s_waitcnt vmcnt(4)" ::: "memory");
    __builtin_amdgcn_s_barrier();
    __builtin_amdgcn_sched_barrier(0);

    const int KT = H_DIM / 32;   // 128
    for (int kt = 0; kt < KT; ++kt) {
        COMPUTE1(kt & 1);
        __builtin_amdgcn_s_barrier();            // all waves done reading cur
        __builtin_amdgcn_sched_barrier(0);
        if (kt + 2 < KT) STAGE1(kt & 1, kt + 2); // overwrite cur with kt+2
        if (kt + 1 < KT) {
            if (kt + 2 < KT) asm volatile("s_waitcnt vmcnt(4)" ::: "memory");
            else             asm volatile("s_waitcnt vmcnt(0)" ::: "memory");
            __builtin_amdgcn_s_barrier();        // s(kt+1) fully landed
            __builtin_amdgcn_sched_barrier(0);
        }
    }
#undef STAGE1
#undef COMPUTE1

    // epilogue: silu(g)*u*pw -> Ht (tiled layout)
    const int r4 = fsel * 4;
    #pragma unroll
    for (int mf = 0; mf < 4; ++mf)
        #pragma unroll
        for (int nf = 0; nf < 4; ++nf) {
            const int col = n0 + wc * 64 + nf * 16 + frow;
            const size_t cbase = (((size_t)tile * 64 + (col >> 5)) * 8192)
                               + (size_t)((col >> 3) & 3) * 2048 + (col & 7);
            #pragma unroll
            for (int j = 0; j < 4; ++j) {
                int rr = wr * 64 + mf * 16 + r4 + j;
                if (rr < rows) {
                    float g = accg[mf][nf][j];
                    float u = accu[mf][nf][j];
                    float sig = 1.f / (1.f + __expf(-g));
                    Ht[cbase + (size_t)rr * 8] = f2bf(g * sig * u * sPw[rr]);
                }
            }
        }
}

__global__ __launch_bounds__(512, 4) void gemm2b_kernel(
    const short* __restrict__ Ht,       // [40][64][4][256][8]
    const short* __restrict__ Wot,      // [E][16][64][4][256][8]
    const int* __restrict__ pair_token,
    const int* __restrict__ t1_expert, const int* __restrict__ t1_row0,
    const int* __restrict__ t1_rows,
    float* __restrict__ out)            // [T][H]
{
    const int b = blockIdx.x;
    const int l = (b & 7) * 80 + (b >> 3);
    const int tile  = l % 40;
    const int n0idx = l / 40;            // over H/256
    const int rows = t1_rows[tile];
    if (rows == 0) return;
    const int e    = t1_expert[tile];
    const int row0 = t1_row0[tile];
    const int n0   = n0idx * 256;

    __shared__ short stg[2][16384];      // 64 KB -> 2 blocks/CU
    __shared__ int   sTok[BM1];

    const int tid  = threadIdx.x;
    const int lane = tid & 63;
    const int w    = tid >> 6;
    const int wof  = w * 512;

    if (tid < BM1) sTok[tid] = pair_token[row0 + min(tid, rows - 1)];
    __syncthreads();

    const short* aT = Ht  + (size_t)tile * 524288 + (size_t)tid * 8;
    const short* bT = Wot + ((size_t)e * 16 + n0idx) * 524288 + (size_t)tid * 8;

    const int wr = w >> 1, wc = w & 1;
    const int frow = lane & 15, fsel = lane >> 4;

    f32x4v acc[4][8];
    #pragma unroll
    for (int mf = 0; mf < 4; ++mf)
        #pragma unroll
        for (int nf = 0; nf < 8; ++nf) acc[mf][nf] = (f32x4v)0.f;

#define STAGE2(s, kt) do { \
        short* st_ = &stg[s][0] + wof; \
        const size_t ko_ = (size_t)(kt); \
        load_lds16(aT + ko_ * 8192,        st_); \
        load_lds16(aT + ko_ * 8192 + 4096, st_ + 4096); \
        load_lds16(bT + ko_ * 8192,        st_ + 8192); \
        load_lds16(bT + ko_ * 8192 + 4096, st_ + 12288); \
    } while (0)

#define COMPUTE2(s) do { \
        const short* st_ = &stg[s][0]; \
        bf16x8 af[4], bf_[8]; \
        _Pragma("unroll") \
        for (int mf = 0; mf < 4; ++mf) \
            af[mf] = *(const bf16x8*)(st_ + (fsel * 256 + wr * 64 + mf * 16 + frow) * 8); \
        _Pragma("unroll") \
        for (int nf = 0; nf < 8; ++nf) \
            bf_[nf] = *(const bf16x8*)(st_ + (1024 + fsel * 256 + wc * 128 + nf * 16 + frow) * 8); \
        __builtin_amdgcn_s_setprio(1); \
        _Pragma("unroll") \
        for (int nf = 0; nf < 8; ++nf) \
            _Pragma("unroll") \
            for (int mf = 0; mf < 4; ++mf) \
                acc[mf][nf] = __builtin_amdgcn_mfma_f32_16x16x32_bf16(af[mf], bf_[nf], acc[mf][nf], 0, 0, 0); \
        __builtin_amdgcn_s_setprio(0); \
    } while (0)

    STAGE2(0, 0); STAGE2(1, 1);
    asm volatile("s_waitcnt vmcnt(4)" ::: "memory");
    __builtin_amdgcn_s_barrier();
    __builtin_amdgcn_sched_barrier(0);

    const int KT = I_DIM / 32;   // 64
    for (int kt = 0; kt < KT; ++kt) {
        COMPUTE2(kt & 1);
        __builtin_amdgcn_s_barrier();
        __builtin_amdgcn_sched_barrier(0);
        if (kt + 2 < KT) STAGE2(kt & 1, kt + 2);
        if (kt + 1 < KT) {
            if (kt + 2 < KT) asm volatile("s_waitcnt vmcnt(4)" ::: "memory");
            else             asm volatile("s_waitcnt vmcnt(0)" ::: "memory");
            __builtin_amdgcn_s_barrier();
            __builtin_amdgcn_sched_barrier(0);
        }
    }
#undef STAGE2
#undef COMPUTE2

    const int r4 = fsel * 4;
    #pragma unroll
    for (int mf = 0; mf < 4; ++mf)
        #pragma unroll
        for (int nf = 0; nf < 8; ++nf)
            #pragma unroll
            for (int j = 0; j < 4; ++j) {
                int rr = wr * 64 + mf * 16 + r4 + j;
                if (rr < rows) {
                    int col = n0 + wc * 128 + nf * 16 + frow;
                    atomicAdd(out + (size_t)sTok[rr] * H_DIM + col, acc[mf][nf][j]);
                }
            }
}

// ================= FALLBACK PATH (R3) =================
__global__ __launch_bounds__(512, 2) void gemm1_kernel(
    const short* __restrict__ Xbf, const float* __restrict__ Wi0, const float* __restrict__ Wi1,
    const int* __restrict__ pair_token, const float* __restrict__ pair_w,
    const int* __restrict__ t1_expert, const int* __restrict__ t1_row0, const int* __restrict__ t1_rows,
    short* __restrict__ Hbuf)
{
    const int tile = blockIdx.x;
    const int rows = t1_rows[tile];
    if (rows == 0) return;
    const int e    = t1_expert[tile];
    const int row0 = t1_row0[tile];
    const int n0   = blockIdx.y * BN1;

    __shared__ short sA [2][BM1][BK1];
    __shared__ short sB0[2][BN1][BK1 + 8];
    __shared__ short sB1[2][BN1][BK1 + 8];
    __shared__ int   sTok[BM1];
    __shared__ float sPw [BM1];

    const int tid  = threadIdx.x;
    const int lane = tid & 63;
    const int w    = tid >> 6;

    if (tid < BM1) {
        int tr = min(tid, rows - 1);
        sTok[tid] = pair_token[row0 + tr];
        sPw[tid]  = (tid < rows) ? pair_w[row0 + tid] : 0.f;
    }
    __syncthreads();

    const short* aSrc[4];
    #pragma unroll
    for (int i = 0; i < 4; ++i) {
        int r = w * 32 + i * 8 + (lane >> 3);
        int j = lane & 7;
        aSrc[i] = Xbf + (size_t)sTok[r] * H_DIM + ((j ^ (r & 7)) * 8);
    }

    const int brow = tid >> 2;
    const int bq   = tid & 3;
    const size_t wboff = ((size_t)e * I_DIM + (n0 + brow)) * H_DIM + bq * 16;
    const float* b0p = Wi0 + wboff;
    const float* b1p = Wi1 + wboff;

    const int wr   = w >> 1;
    const int wc   = w & 1;
    const int frow = lane & 15;
    const int fsel = lane >> 4;

    f32x4v accg[4][4], accu[4][4];
    #pragma unroll
    for (int mf = 0; mf < 4; ++mf)
        #pragma unroll
        for (int nf = 0; nf < 4; ++nf) { accg[mf][nf] = (f32x4v)0.f; accu[mf][nf] = (f32x4v)0.f; }

    f32x4v rb0[4], rb1[4];

    #pragma unroll
    for (int i = 0; i < 4; ++i)
        load_lds16(aSrc[i], &sA[0][w * 32 + i * 8][0]);
    #pragma unroll
    for (int i = 0; i < 4; ++i) { rb0[i] = *(const f32x4v*)(b0p + i * 4); rb1[i] = *(const f32x4v*)(b1p + i * 4); }
    {
        short* d0 = &sB0[0][brow][bq * 16];
        *(bf16x8*)d0       = pack8(rb0[0], rb0[1]);
        *(bf16x8*)(d0 + 8) = pack8(rb0[2], rb0[3]);
        short* d1 = &sB1[0][brow][bq * 16];
        *(bf16x8*)d1       = pack8(rb1[0], rb1[1]);
        *(bf16x8*)(d1 + 8) = pack8(rb1[2], rb1[3]);
    }
    __syncthreads();

    const int KT = H_DIM / BK1;
    for (int kt = 0; kt < KT; ++kt) {
        const int cur = kt & 1, nxt = cur ^ 1;
        if (kt + 1 < KT) {
            #pragma unroll
            for (int i = 0; i < 4; ++i)
                load_lds16(aSrc[i] + (kt + 1) * BK1, &sA[nxt][w * 32 + i * 8][0]);
            const float* p0 = b0p + (kt + 1) * BK1;
            const float* p1 = b1p + (kt + 1) * BK1;
            #pragma unroll
            for (int i = 0; i < 4; ++i) { rb0[i] = *(const f32x4v*)(p0 + i * 4); rb1[i] = *(const f32x4v*)(p1 + i * 4); }
        }
        #pragma unroll
        for (int h = 0; h < 2; ++h) {
            bf16x8 af[4], b0f[4], b1f[4];
            #pragma unroll
            for (int mf = 0; mf < 4; ++mf) {
                int ar = wr * 64 + mf * 16 + frow;
                int c  = (h * 4 + fsel) ^ (ar & 7);
                af[mf] = *(const bf16x8*)((const char*)&sA[cur][0][0] + ar * (BK1 * 2) + c * 16);
            }
            #pragma unroll
            for (int nf = 0; nf < 4; ++nf) {
                int br = wc * 64 + nf * 16 + frow;
                b0f[nf] = *(const bf16x8*)&sB0[cur][br][h * 32 + fsel * 8];
                b1f[nf] = *(const bf16x8*)&sB1[cur][br][h * 32 + fsel * 8];
            }
            #pragma unroll
            for (int nf = 0; nf < 4; ++nf)
                #pragma unroll
                for (int mf = 0; mf < 4; ++mf) {
                    accg[mf][nf] = __builtin_amdgcn_mfma_f32_16x16x32_bf16(af[mf], b0f[nf], accg[mf][nf], 0, 0, 0);
                    accu[mf][nf] = __builtin_amdgcn_mfma_f32_16x16x32_bf16(af[mf], b1f[nf], accu[mf][nf], 0, 0, 0);
                }
        }
        if (kt + 1 < KT) {
            short* d0 = &sB0[nxt][brow][bq * 16];
            *(bf16x8*)d0       = pack8(rb0[0], rb0[1]);
            *(bf16x8*)(d0 + 8) = pack8(rb0[2], rb0[3]);
            short* d1 = &sB1[nxt][brow][bq * 16];
            *(bf16x8*)d1       = pack8(rb1[0], rb1[1]);
            *(bf16x8*)(d1 + 8) = pack8(rb1[2], rb1[3]);
        }
        __syncthreads();
    }

    const int r4 = fsel * 4;
    #pragma unroll
    for (int mf = 0; mf < 4; ++mf)
        #pragma unroll
        for (int nf = 0; nf < 4; ++nf)
            #pragma unroll
            for (int j = 0; j < 4; ++j) {
                int rr = wr * 64 + mf * 16 + r4 + j;
                if (rr < rows) {
                    float g = accg[mf][nf][j];
                    float u = accu[mf][nf][j];
                    float sig = 1.f / (1.f + __expf(-g));
                    float v = g * sig * u * sPw[rr];
                    int col = n0 + wc * 64 + nf * 16 + frow;
                    Hbuf[(size_t)(row0 + rr) * I_DIM + col] = f2bf(v);
                }
            }
}

__global__ __launch_bounds__(256, 2) void gemm2_kernel(
    const short* __restrict__ Hbuf, const float* __restrict__ Wo,
    const int* __restrict__ pair_token,
    const int* __restrict__ tile_expert, const int* __restrict__ tile_row0,
    const int* __restrict__ tile_rows,
    float* __restrict__ out)
{
    const int tile = blockIdx.x;
    const int rows = tile_rows[tile];
    if (rows == 0) return;
    const int e    = tile_expert[tile];
    const int row0 = tile_row0[tile];
    const int n0   = blockIdx.y * 256;

    __shared__ short sA[BM][BK + 8];
    __shared__ short sB[256][BK + 8];
    __shared__ int   sTok[BM];

    const int tid = threadIdx.x;
    if (tid < BM) sTok[tid] = pair_token[row0 + min(tid, rows - 1)];
    __syncthreads();

    const int srow  = tid >> 1;
    const int shalf = tid & 1;

    const short* aptr = Hbuf + (size_t)(row0 + min(srow, rows - 1)) * I_DIM + shalf * 16;
    const float* bptrA = Wo + ((size_t)e * H_DIM + (n0 + srow))       * I_DIM + shalf * 16;
    const float* bptrB = Wo + ((size_t)e * H_DIM + (n0 + srow + 128)) * I_DIM + shalf * 16;

    bf16x8 ra[2];
    f32x4v rbA[4], rbB[4];
    f32x4v acc[4][8];
    #pragma unroll
    for (int mf = 0; mf < 4; ++mf)
        #pragma unroll
        for (int nf = 0; nf < 8; ++nf) acc[mf][nf] = (f32x4v)0.f;

    const int lane = tid & 63;
    const int wid  = tid >> 6;
    const int wr   = wid >> 1;
    const int wc   = wid & 1;
    const int frow = lane & 15;
    const int fk   = (lane >> 4) * 8;

    ra[0] = *(const bf16x8*)(aptr);
    ra[1] = *(const bf16x8*)(aptr + 8);
    #pragma unroll
    for (int i = 0; i < 4; ++i) { rbA[i] = *(const f32x4v*)(bptrA + i * 4); rbB[i] = *(const f32x4v*)(bptrB + i * 4); }

    const int KT = I_DIM / BK;
    for (int kt = 0; kt < KT; ++kt) {
        __syncthreads();
        *(bf16x8*)&sA[srow][shalf * 16]           = ra[0];
        *(bf16x8*)&sA[srow][shalf * 16 + 8]       = ra[1];
        *(bf16x8*)&sB[srow][shalf * 16]           = pack8(rbA[0], rbA[1]);
        *(bf16x8*)&sB[srow][shalf * 16 + 8]       = pack8(rbA[2], rbA[3]);
        *(bf16x8*)&sB[srow + 128][shalf * 16]     = pack8(rbB[0], rbB[1]);
        *(bf16x8*)&sB[srow + 128][shalf * 16 + 8] = pack8(rbB[2], rbB[3]);
        __syncthreads();

        if (kt + 1 < KT) {
            const int k = (kt + 1) * BK;
            ra[0] = *(const bf16x8*)(aptr + k);
            ra[1] = *(const bf16x8*)(aptr + k + 8);
            #pragma unroll
            for (int i = 0; i < 4; ++i) { rbA[i] = *(const f32x4v*)(bptrA + k + i * 4); rbB[i] = *(const f32x4v*)(bptrB + k + i * 4); }
        }

        bf16x8 af[4];
        #pragma unroll
        for (int mf = 0; mf < 4; ++mf)
            af[mf] = *(const bf16x8*)&sA[wr * 64 + mf * 16 + frow][fk];
        #pragma unroll
        for (int nf = 0; nf < 8; ++nf) {
            bf16x8 bfv = *(const bf16x8*)&sB[wc * 128 + nf * 16 + frow][fk];
            #pragma unroll
            for (int mf = 0; mf < 4; ++mf)
                acc[mf][nf] = __builtin_amdgcn_mfma_f32_16x16x32_bf16(af[mf], bfv, acc[mf][nf], 0, 0, 0);
        }
    }

    const int r4 = (lane >> 4) * 4;
    #pragma unroll
    for (int mf = 0; mf < 4; ++mf)
        #pragma unroll
        for (int nf = 0; nf < 8; ++nf)
            #pragma unroll
            for (int j = 0; j < 4; ++j) {
                int rr = wr * 64 + mf * 16 + r4 + j;
                if (rr < rows) {
                    int col = n0 + wc * 128 + nf * 16 + (lane & 15);
                    atomicAdd(out + (size_t)sTok[rr] * H_DIM + col, acc[mf][nf][j]);
                }
            }
}

// ---------------- launch ----------------
extern "C" void kernel_launch(void* const* d_in, const int* in_sizes, int n_in,
                              void* d_out, int out_size, void* d_ws, size_t ws_size,
                              hipStream_t stream)
{
    (void)in_sizes; (void)n_in;
    const float* X     = (const float*)d_in[0];
    const float* topw  = (const float*)d_in[1];
    const int*   topid = (const int*)d_in[2];
    const float* Wi0   = (const float*)d_in[3];
    const float* Wi1   = (const float*)d_in[4];
    const float* Wo    = (const float*)d_in[5];
    float* out = (float*)d_out;

    char* ws = (char*)d_ws;
    int*   pair_token  = (int*)ws;
    float* pair_w      = (float*)(ws + NPAIR * 4);
    int*   tile_expert = (int*)(ws + NPAIR * 8);
    int*   tile_row0   = tile_expert + MAXT;
    int*   tile_rows   = tile_row0 + MAXT;
    int*   t1_expert   = tile_rows + MAXT;
    int*   t1_row0     = t1_expert + MAXT1;
    int*   t1_rows     = t1_row0 + MAXT1;

    route_kernel<<<1, 256, 0, stream>>>(topid, topw, pair_token, pair_w,
                                        tile_expert, tile_row0, tile_rows,
                                        t1_expert, t1_row0, t1_rows);

    if (ws_size >= NEED_NEW) {
        short* Ht  = (short*)(ws + HT_OFF);
        short* W0t = (short*)(ws + W0_OFF);
        short* W1t = (short*)(ws + W1_OFF);
        short* At  = (short*)(ws + AT_OFF);
        short* Wot = W0t;   // overlays Wi0b after gemm1b

        hipMemsetAsync(d_out, 0, (size_t)out_size * sizeof(float), stream);

        aprep_kernel<<<MAXT1 * 256 * 512 / 256, 256, 0, stream>>>(X, pair_token, t1_row0, t1_rows, At);
        wprep_kernel<<<(int)((size_t)N_EXP * I_DIM * 512 / 256), 256, 0, stream>>>(Wi0, W0t);
        wprep_kernel<<<(int)((size_t)N_EXP * I_DIM * 512 / 256), 256, 0, stream>>>(Wi1, W1t);

        gemm1b_kernel<<<MAXT1 * 16, 512, 0, stream>>>(
            At, W0t, W1t, pair_w, t1_expert, t1_row0, t1_rows, Ht);

        woprep_kernel<<<(int)((size_t)N_EXP * H_DIM * 256 / 256), 256, 0, stream>>>(Wo, Wot);

        gemm2b_kernel<<<MAXT1 * 16, 512, 0, stream>>>(
            Ht, Wot, pair_token, t1_expert, t1_row0, t1_rows, out);
    } else {
        short* Hbuf = (short*)(ws + (1 << 20));
        short* Xbf  = (short*)d_out;

        cvt_kernel<<<T_TOK * H_DIM / (256 * 8), 256, 0, stream>>>(X, Xbf);

        gemm1_kernel<<<dim3(MAXT1, I_DIM / BN1), 512, 0, stream>>>(
            Xbf, Wi0, Wi1, pair_token, pair_w, t1_expert, t1_row0, t1_rows, Hbuf);

        hipMemsetAsync(d_out, 0, (size_t)out_size * sizeof(float), stream);

        gemm2_kernel<<<dim3(MAXT, H_DIM / 256), 256, 0, stream>>>(
            Hbuf, Wo, pair_token, tile_expert, tile_row0, tile_rows, out);
    }
}

// Round 7
// 1157.726 us; speedup vs baseline: 4.9225x; 4.9225x over previous
//
#include <hip/hip_runtime.h>
#include <hip/hip_bf16.h>

#define T_TOK 4096
#define H_DIM 4096
#define I_DIM 2048
#define N_EXP 8
#define TOPK  2
#define NPAIR (T_TOK*TOPK)          // 8192
#define BM    128                   // fallback gemm2 M-tile
#define BK    32
#define MAXT  (NPAIR/BM + N_EXP)    // 72
#define BM1   256
#define BN1   128
#define MAXT1 (NPAIR/BM1 + N_EXP)   // 40

// ---- tiled-workspace offsets (bytes) ----
#define HT_OFF   ((size_t)1 << 20)
#define W0_OFF   ((size_t)45 << 20)
#define W1_OFF   (W0_OFF + 134217728ull)
#define AT_OFF   (W1_OFF + 134217728ull)
#define NEED_NEW (AT_OFF + 83886080ull)             // ~381 MB

typedef __attribute__((ext_vector_type(8))) short  bf16x8;
typedef __attribute__((ext_vector_type(4))) float  f32x4v;

__device__ __forceinline__ short f2bf(float f) {
    __hip_bfloat16 h = __float2bfloat16(f);
    return __builtin_bit_cast(short, h);
}

__device__ __forceinline__ bf16x8 pack8(f32x4v a, f32x4v b) {
    bf16x8 r;
    r[0]=f2bf(a[0]); r[1]=f2bf(a[1]); r[2]=f2bf(a[2]); r[3]=f2bf(a[3]);
    r[4]=f2bf(b[0]); r[5]=f2bf(b[1]); r[6]=f2bf(b[2]); r[7]=f2bf(b[3]);
    return r;
}

__device__ __forceinline__ void load_lds16(const short* g, short* l) {
    __builtin_amdgcn_global_load_lds(
        (const __attribute__((address_space(1))) void*)g,
        (__attribute__((address_space(3))) void*)l, 16, 0, 0);
}

// ---------------- fp32 -> bf16 plain (fallback X path) ----------------
__global__ void cvt_kernel(const float* __restrict__ X, short* __restrict__ Xbf) {
    const size_t i = ((size_t)blockIdx.x * 256 + threadIdx.x) * 8;
    f32x4v a = *(const f32x4v*)(X + i);
    f32x4v b = *(const f32x4v*)(X + i + 4);
    *(bf16x8*)(Xbf + i) = pack8(a, b);
}

// ---------------- routing ----------------
__global__ void route_kernel(const int* __restrict__ ids, const float* __restrict__ wts,
                             int* __restrict__ pair_token, float* __restrict__ pair_w,
                             int* __restrict__ tile_expert, int* __restrict__ tile_row0,
                             int* __restrict__ tile_rows,
                             int* __restrict__ t1_expert, int* __restrict__ t1_row0,
                             int* __restrict__ t1_rows)
{
    __shared__ int scn[256][N_EXP];
    const int tid = threadIdx.x;
    const int PPT = NPAIR / 256;
    const int base = tid * PPT;

    int c[N_EXP], orig[N_EXP];
    #pragma unroll
    for (int e = 0; e < N_EXP; ++e) c[e] = 0;
    for (int p = 0; p < PPT; ++p) c[ids[base + p]]++;
    #pragma unroll
    for (int e = 0; e < N_EXP; ++e) { orig[e] = c[e]; scn[tid][e] = c[e]; }
    __syncthreads();

    for (int off = 1; off < 256; off <<= 1) {
        int add[N_EXP];
        #pragma unroll
        for (int e = 0; e < N_EXP; ++e) add[e] = (tid >= off) ? scn[tid - off][e] : 0;
        __syncthreads();
        #pragma unroll
        for (int e = 0; e < N_EXP; ++e) { c[e] += add[e]; scn[tid][e] = c[e]; }
        __syncthreads();
    }

    int segs[N_EXP + 1];
    {
        int run = 0;
        #pragma unroll
        for (int e = 0; e < N_EXP; ++e) { segs[e] = run; run += scn[255][e]; }
        segs[N_EXP] = run;
    }
    int pos[N_EXP];
    #pragma unroll
    for (int e = 0; e < N_EXP; ++e) pos[e] = segs[e] + c[e] - orig[e];

    for (int p = 0; p < PPT; ++p) {
        int pp = base + p;
        int e = ids[pp];
        int q = pos[e]++;
        pair_token[q] = pp / TOPK;
        pair_w[q]     = wts[pp];
    }

    if (tid == 0) {
        int t = 0;
        for (int e = 0; e < N_EXP; ++e) {
            int s = segs[e], en = segs[e + 1];
            for (int r = s; r < en; r += BM) {
                tile_expert[t] = e; tile_row0[t] = r; tile_rows[t] = min(BM, en - r); ++t;
            }
        }
        for (; t < MAXT; ++t) { tile_expert[t] = 0; tile_row0[t] = 0; tile_rows[t] = 0; }

        t = 0;
        for (int e = 0; e < N_EXP; ++e) {
            int s = segs[e], en = segs[e + 1];
            for (int r = s; r < en; r += BM1) {
                t1_expert[t] = e; t1_row0[t] = r; t1_rows[t] = min(BM1, en - r); ++t;
            }
        }
        for (; t < MAXT1; ++t) { t1_expert[t] = 0; t1_row0[t] = 0; t1_rows[t] = 0; }
    }
}

// ================= coalesced LDS-transpose preps =================
#define PRP 132

// Wi (E,I,H) fp32 -> Wt [e][ib][kt 128][q 4][r 128][x 8]
__global__ __launch_bounds__(256) void wprep_kernel(const float* __restrict__ W, short* __restrict__ Wt) {
    const int bid = blockIdx.x;          // 8 * 16 * 32 = 4096
    const int e   = bid >> 9;
    const int ib  = (bid >> 5) & 15;
    const int ktg = bid & 31;
    __shared__ short lds[128][PRP];
    const int tid = threadIdx.x;
    const float* src0 = W + ((size_t)(e * 2048 + ib * 128)) * 4096 + ktg * 128;
    #pragma unroll
    for (int it = 0; it < 8; ++it) {
        int r  = it * 16 + (tid >> 4);
        int hc = (tid & 15) * 8;
        const float* s = src0 + (size_t)r * 4096 + hc;
        f32x4v a = *(const f32x4v*)s;
        f32x4v b = *(const f32x4v*)(s + 4);
        *(bf16x8*)&lds[r][hc] = pack8(a, b);
    }
    __syncthreads();
    short* dst = Wt + ((size_t)(e * 16 + ib) * 128 + ktg * 4) * 4096;
    #pragma unroll
    for (int it = 0; it < 8; ++it) {
        int off = it * 2048 + tid * 8;
        int ktl = off >> 12;
        int q   = (off >> 10) & 3;
        int rl  = (off >> 3) & 127;
        bf16x8 v = *(const bf16x8*)&lds[rl][ktl * 32 + q * 8];
        *(bf16x8*)(dst + (size_t)ktl * 4096 + q * 1024 + rl * 8) = v;
    }
}

// Wo (E,H,I) fp32 -> Wot [e][hb][kt 64][q 4][r 256][x 8]
__global__ __launch_bounds__(256) void woprep_kernel(const float* __restrict__ W, short* __restrict__ Wt) {
    const int bid = blockIdx.x;          // 8 * 16 * 2 * 16 = 4096
    const int e   = bid >> 9;
    const int hb  = (bid >> 5) & 15;
    const int rh  = (bid >> 4) & 1;
    const int ktg = bid & 15;
    __shared__ short lds[128][PRP];
    const int tid = threadIdx.x;
    const float* src0 = W + ((size_t)(e * 4096 + hb * 256 + rh * 128)) * 2048 + ktg * 128;
    #pragma unroll
    for (int it = 0; it < 8; ++it) {
        int r  = it * 16 + (tid >> 4);
        int hc = (tid & 15) * 8;
        const float* s = src0 + (size_t)r * 2048 + hc;
        f32x4v a = *(const f32x4v*)s;
        f32x4v b = *(const f32x4v*)(s + 4);
        *(bf16x8*)&lds[r][hc] = pack8(a, b);
    }
    __syncthreads();
    short* dst = Wt + (((size_t)(e * 16 + hb) * 64 + ktg * 4) * 8192) + rh * 1024;
    #pragma unroll
    for (int it = 0; it < 8; ++it) {
        int off = it * 2048 + tid * 8;
        int ktl = off >> 12;
        int q   = (off >> 10) & 3;
        int rl  = (off >> 3) & 127;
        bf16x8 v = *(const bf16x8*)&lds[rl][ktl * 32 + q * 8];
        *(bf16x8*)(dst + (size_t)ktl * 8192 + q * 2048 + rl * 8) = v;
    }
}

// X gather -> At [tile][kt 128][q 4][r 256][x 8]
__global__ __launch_bounds__(256) void aprep_kernel(const float* __restrict__ X,
                             const int* __restrict__ pair_token,
                             const int* __restrict__ t1_row0, const int* __restrict__ t1_rows,
                             short* __restrict__ At) {
    const int bid  = blockIdx.x;         // 40 * 2 * 32 = 2560
    const int tile = bid >> 6;
    const int rh   = (bid >> 5) & 1;
    const int ktg  = bid & 31;
    const int rows = t1_rows[tile];
    if (rows == 0) return;
    const int row0 = t1_row0[tile];
    __shared__ short lds[128][PRP];
    const int tid = threadIdx.x;
    #pragma unroll
    for (int it = 0; it < 8; ++it) {
        int r  = it * 16 + (tid >> 4);
        int hc = (tid & 15) * 8;
        int tok = pair_token[row0 + min(rh * 128 + r, rows - 1)];
        const float* s = X + (size_t)tok * 4096 + ktg * 128 + hc;
        f32x4v a = *(const f32x4v*)s;
        f32x4v b = *(const f32x4v*)(s + 4);
        *(bf16x8*)&lds[r][hc] = pack8(a, b);
    }
    __syncthreads();
    short* dst = At + (((size_t)tile * 128 + ktg * 4) * 8192) + rh * 1024;
    #pragma unroll
    for (int it = 0; it < 8; ++it) {
        int off = it * 2048 + tid * 8;
        int ktl = off >> 12;
        int q   = (off >> 10) & 3;
        int rl  = (off >> 3) & 127;
        bf16x8 v = *(const bf16x8*)&lds[rl][ktl * 32 + q * 8];
        *(bf16x8*)(dst + (size_t)ktl * 8192 + q * 2048 + rl * 8) = v;
    }
}

// ================= tiled-stream GEMMs: linear gload_lds, 4-stage vmcnt(8) ring =================
// (R5-proven schedule; only block->work mapping changed: XCD-concurrent A-tile sharing)

__global__ __launch_bounds__(512, 2) void gemm1b_kernel(
    const short* __restrict__ At,       // [40][128][4][256][8]
    const short* __restrict__ W0t,      // [E][16][128][4][128][8]
    const short* __restrict__ W1t,
    const float* __restrict__ pair_w,
    const int* __restrict__ t1_expert, const int* __restrict__ t1_row0,
    const int* __restrict__ t1_rows,
    short* __restrict__ Ht)             // [40][64][4][256][8]
{
    // XCD A-sharing: the 16 blocks of one tile run concurrently on one XCD
    const int b    = blockIdx.x;
    const int xcd  = b & 7;
    const int i    = b >> 3;             // 0..79
    const int tile  = xcd * 5 + (i >> 4);
    const int n0idx = i & 15;            // over I/128
    const int rows = t1_rows[tile];
    if (rows == 0) return;
    const int e    = t1_expert[tile];
    const int row0 = t1_row0[tile];
    const int n0   = n0idx * BN1;

    __shared__ short stg[4][16384];      // 128 KB
    __shared__ float sPw[BM1];

    const int tid  = threadIdx.x;
    const int lane = tid & 63;
    const int w    = tid >> 6;
    const int wof  = w * 512;

    if (tid < BM1) sPw[tid] = (tid < rows) ? pair_w[row0 + tid] : 0.f;
    __syncthreads();

    const short* aT  = At  + (size_t)tile * 1048576 + (size_t)tid * 8;
    const short* b0T = W0t + ((size_t)e * 16 + n0idx) * 524288 + (size_t)tid * 8;
    const short* b1T = W1t + ((size_t)e * 16 + n0idx) * 524288 + (size_t)tid * 8;

    const int wr = w >> 1, wc = w & 1;
    const int frow = lane & 15, fsel = lane >> 4;

    f32x4v accg[4][4], accu[4][4];
    #pragma unroll
    for (int mf = 0; mf < 4; ++mf)
        #pragma unroll
        for (int nf = 0; nf < 4; ++nf) { accg[mf][nf] = (f32x4v)0.f; accu[mf][nf] = (f32x4v)0.f; }

#define STAGE1(s, kt) do { \
        short* st_ = &stg[s][0] + wof; \
        const size_t ko_ = (size_t)(kt); \
        load_lds16(aT  + ko_ * 8192,        st_); \
        load_lds16(aT  + ko_ * 8192 + 4096, st_ + 4096); \
        load_lds16(b0T + ko_ * 4096,        st_ + 8192); \
        load_lds16(b1T + ko_ * 4096,        st_ + 12288); \
    } while (0)

#define COMPUTE1(s) do { \
        const short* st_ = &stg[s][0]; \
        bf16x8 af[4], b0f[4], b1f[4]; \
        _Pragma("unroll") \
        for (int mf = 0; mf < 4; ++mf) \
            af[mf] = *(const bf16x8*)(st_ + (fsel * 256 + wr * 64 + mf * 16 + frow) * 8); \
        _Pragma("unroll") \
        for (int nf = 0; nf < 4; ++nf) { \
            b0f[nf] = *(const bf16x8*)(st_ + (1024 + fsel * 128 + wc * 64 + nf * 16 + frow) * 8); \
            b1f[nf] = *(const bf16x8*)(st_ + (1536 + fsel * 128 + wc * 64 + nf * 16 + frow) * 8); \
        } \
        __builtin_amdgcn_s_setprio(1); \
        _Pragma("unroll") \
        for (int nf = 0; nf < 4; ++nf) \
            _Pragma("unroll") \
            for (int mf = 0; mf < 4; ++mf) { \
                accg[mf][nf] = __builtin_amdgcn_mfma_f32_16x16x32_bf16(af[mf], b0f[nf], accg[mf][nf], 0, 0, 0); \
                accu[mf][nf] = __builtin_amdgcn_mfma_f32_16x16x32_bf16(af[mf], b1f[nf], accu[mf][nf], 0, 0, 0); \
            } \
        __builtin_amdgcn_s_setprio(0); \
    } while (0)

    STAGE1(0, 0); STAGE1(1, 1); STAGE1(2, 2);
    asm volatile("s_waitcnt vmcnt(8)" ::: "memory");
    __builtin_amdgcn_s_barrier();
    __builtin_amdgcn_sched_barrier(0);

    const int KT = H_DIM / 32;   // 128
    for (int kt = 0; kt < KT; ++kt) {
        const int cur = kt & 3;
        if (kt + 3 < KT) STAGE1((kt + 3) & 3, kt + 3);
        COMPUTE1(cur);
        if (kt + 1 < KT) {
            __builtin_amdgcn_sched_barrier(0);
            if (kt + 3 < KT)      asm volatile("s_waitcnt vmcnt(8)" ::: "memory");
            else if (kt + 2 < KT) asm volatile("s_waitcnt vmcnt(4)" ::: "memory");
            else                  asm volatile("s_waitcnt vmcnt(0)" ::: "memory");
            __builtin_amdgcn_s_barrier();
            __builtin_amdgcn_sched_barrier(0);
        }
    }
#undef STAGE1
#undef COMPUTE1

    // epilogue: silu(g)*u*pw -> Ht (tiled layout)
    const int r4 = fsel * 4;
    #pragma unroll
    for (int mf = 0; mf < 4; ++mf)
        #pragma unroll
        for (int nf = 0; nf < 4; ++nf) {
            const int col = n0 + wc * 64 + nf * 16 + frow;
            const size_t cbase = (((size_t)tile * 64 + (col >> 5)) * 8192)
                               + (size_t)((col >> 3) & 3) * 2048 + (col & 7);
            #pragma unroll
            for (int j = 0; j < 4; ++j) {
                int rr = wr * 64 + mf * 16 + r4 + j;
                if (rr < rows) {
                    float g = accg[mf][nf][j];
                    float u = accu[mf][nf][j];
                    float sig = 1.f / (1.f + __expf(-g));
                    Ht[cbase + (size_t)rr * 8] = f2bf(g * sig * u * sPw[rr]);
                }
            }
        }
}

__global__ __launch_bounds__(512, 2) void gemm2b_kernel(
    const short* __restrict__ Ht,       // [40][64][4][256][8]
    const short* __restrict__ Wot,      // [E][16][64][4][256][8]
    const int* __restrict__ pair_token,
    const int* __restrict__ t1_expert, const int* __restrict__ t1_row0,
    const int* __restrict__ t1_rows,
    float* __restrict__ out)            // [T][H]
{
    const int b    = blockIdx.x;
    const int xcd  = b & 7;
    const int i    = b >> 3;
    const int tile  = xcd * 5 + (i >> 4);
    const int n0idx = i & 15;            // over H/256
    const int rows = t1_rows[tile];
    if (rows == 0) return;
    const int e    = t1_expert[tile];
    const int row0 = t1_row0[tile];
    const int n0   = n0idx * 256;

    __shared__ short stg[4][16384];      // 128 KB
    __shared__ int   sTok[BM1];

    const int tid  = threadIdx.x;
    const int lane = tid & 63;
    const int w    = tid >> 6;
    const int wof  = w * 512;

    if (tid < BM1) sTok[tid] = pair_token[row0 + min(tid, rows - 1)];
    __syncthreads();

    const short* aT = Ht  + (size_t)tile * 524288 + (size_t)tid * 8;
    const short* bT = Wot + ((size_t)e * 16 + n0idx) * 524288 + (size_t)tid * 8;

    const int wr = w >> 1, wc = w & 1;
    const int frow = lane & 15, fsel = lane >> 4;

    f32x4v acc[4][8];
    #pragma unroll
    for (int mf = 0; mf < 4; ++mf)
        #pragma unroll
        for (int nf = 0; nf < 8; ++nf) acc[mf][nf] = (f32x4v)0.f;

#define STAGE2(s, kt) do { \
        short* st_ = &stg[s][0] + wof; \
        const size_t ko_ = (size_t)(kt); \
        load_lds16(aT + ko_ * 8192,        st_); \
        load_lds16(aT + ko_ * 8192 + 4096, st_ + 4096); \
        load_lds16(bT + ko_ * 8192,        st_ + 8192); \
        load_lds16(bT + ko_ * 8192 + 4096, st_ + 12288); \
    } while (0)

#define COMPUTE2(s) do { \
        const short* st_ = &stg[s][0]; \
        bf16x8 af[4], bf_[8]; \
        _Pragma("unroll") \
        for (int mf = 0; mf < 4; ++mf) \
            af[mf] = *(const bf16x8*)(st_ + (fsel * 256 + wr * 64 + mf * 16 + frow) * 8); \
        _Pragma("unroll") \
        for (int nf = 0; nf < 8; ++nf) \
            bf_[nf] = *(const bf16x8*)(st_ + (1024 + fsel * 256 + wc * 128 + nf * 16 + frow) * 8); \
        __builtin_amdgcn_s_setprio(1); \
        _Pragma("unroll") \
        for (int nf = 0; nf < 8; ++nf) \
            _Pragma("unroll") \
            for (int mf = 0; mf < 4; ++mf) \
                acc[mf][nf] = __builtin_amdgcn_mfma_f32_16x16x32_bf16(af[mf], bf_[nf], acc[mf][nf], 0, 0, 0); \
        __builtin_amdgcn_s_setprio(0); \
    } while (0)

    STAGE2(0, 0); STAGE2(1, 1); STAGE2(2, 2);
    asm volatile("s_waitcnt vmcnt(8)" ::: "memory");
    __builtin_amdgcn_s_barrier();
    __builtin_amdgcn_sched_barrier(0);

    const int KT = I_DIM / 32;   // 64
    for (int kt = 0; kt < KT; ++kt) {
        const int cur = kt & 3;
        if (kt + 3 < KT) STAGE2((kt + 3) & 3, kt + 3);
        COMPUTE2(cur);
        if (kt + 1 < KT) {
            __builtin_amdgcn_sched_barrier(0);
            if (kt + 3 < KT)      asm volatile("s_waitcnt vmcnt(8)" ::: "memory");
            else if (kt + 2 < KT) asm volatile("s_waitcnt vmcnt(4)" ::: "memory");
            else                  asm volatile("s_waitcnt vmcnt(0)" ::: "memory");
            __builtin_amdgcn_s_barrier();
            __builtin_amdgcn_sched_barrier(0);
        }
    }
#undef STAGE2
#undef COMPUTE2

    const int r4 = fsel * 4;
    #pragma unroll
    for (int mf = 0; mf < 4; ++mf)
        #pragma unroll
        for (int nf = 0; nf < 8; ++nf)
            #pragma unroll
            for (int j = 0; j < 4; ++j) {
                int rr = wr * 64 + mf * 16 + r4 + j;
                if (rr < rows) {
                    int col = n0 + wc * 128 + nf * 16 + frow;
                    atomicAdd(out + (size_t)sTok[rr] * H_DIM + col, acc[mf][nf][j]);
                }
            }
}

// ================= FALLBACK PATH (R3) =================
__global__ __launch_bounds__(512, 2) void gemm1_kernel(
    const short* __restrict__ Xbf, const float* __restrict__ Wi0, const float* __restrict__ Wi1,
    const int* __restrict__ pair_token, const float* __restrict__ pair_w,
    const int* __restrict__ t1_expert, const int* __restrict__ t1_row0, const int* __restrict__ t1_rows,
    short* __restrict__ Hbuf)
{
    const int tile = blockIdx.x;
    const int rows = t1_rows[tile];
    if (rows == 0) return;
    const int e    = t1_expert[tile];
    const int row0 = t1_row0[tile];
    const int n0   = blockIdx.y * BN1;

    __shared__ short sA [2][BM1][64];
    __shared__ short sB0[2][BN1][64 + 8];
    __shared__ short sB1[2][BN1][64 + 8];
    __shared__ int   sTok[BM1];
    __shared__ float sPw [BM1];

    const int tid  = threadIdx.x;
    const int lane = tid & 63;
    const int w    = tid >> 6;

    if (tid < BM1) {
        int tr = min(tid, rows - 1);
        sTok[tid] = pair_token[row0 + tr];
        sPw[tid]  = (tid < rows) ? pair_w[row0 + tid] : 0.f;
    }
    __syncthreads();

    const short* aSrc[4];
    #pragma unroll
    for (int i = 0; i < 4; ++i) {
        int r = w * 32 + i * 8 + (lane >> 3);
        int j = lane & 7;
        aSrc[i] = Xbf + (size_t)sTok[r] * H_DIM + ((j ^ (r & 7)) * 8);
    }

    const int brow = tid >> 2;
    const int bq   = tid & 3;
    const size_t wboff = ((size_t)e * I_DIM + (n0 + brow)) * H_DIM + bq * 16;
    const float* b0p = Wi0 + wboff;
    const float* b1p = Wi1 + wboff;

    const int wr   = w >> 1;
    const int wc   = w & 1;
    const int frow = lane & 15;
    const int fsel = lane >> 4;

    f32x4v accg[4][4], accu[4][4];
    #pragma unroll
    for (int mf = 0; mf < 4; ++mf)
        #pragma unroll
        for (int nf = 0; nf < 4; ++nf) { accg[mf][nf] = (f32x4v)0.f; accu[mf][nf] = (f32x4v)0.f; }

    f32x4v rb0[4], rb1[4];

    #pragma unroll
    for (int i = 0; i < 4; ++i)
        load_lds16(aSrc[i], &sA[0][w * 32 + i * 8][0]);
    #pragma unroll
    for (int i = 0; i < 4; ++i) { rb0[i] = *(const f32x4v*)(b0p + i * 4); rb1[i] = *(const f32x4v*)(b1p + i * 4); }
    {
        short* d0 = &sB0[0][brow][bq * 16];
        *(bf16x8*)d0       = pack8(rb0[0], rb0[1]);
        *(bf16x8*)(d0 + 8) = pack8(rb0[2], rb0[3]);
        short* d1 = &sB1[0][brow][bq * 16];
        *(bf16x8*)d1       = pack8(rb1[0], rb1[1]);
        *(bf16x8*)(d1 + 8) = pack8(rb1[2], rb1[3]);
    }
    __syncthreads();

    const int KT = H_DIM / 64;
    for (int kt = 0; kt < KT; ++kt) {
        const int cur = kt & 1, nxt = cur ^ 1;
        if (kt + 1 < KT) {
            #pragma unroll
            for (int i = 0; i < 4; ++i)
                load_lds16(aSrc[i] + (kt + 1) * 64, &sA[nxt][w * 32 + i * 8][0]);
            const float* p0 = b0p + (kt + 1) * 64;
            const float* p1 = b1p + (kt + 1) * 64;
            #pragma unroll
            for (int i = 0; i < 4; ++i) { rb0[i] = *(const f32x4v*)(p0 + i * 4); rb1[i] = *(const f32x4v*)(p1 + i * 4); }
        }
        #pragma unroll
        for (int h = 0; h < 2; ++h) {
            bf16x8 af[4], b0f[4], b1f[4];
            #pragma unroll
            for (int mf = 0; mf < 4; ++mf) {
                int ar = wr * 64 + mf * 16 + frow;
                int c  = (h * 4 + fsel) ^ (ar & 7);
                af[mf] = *(const bf16x8*)((const char*)&sA[cur][0][0] + ar * 128 + c * 16);
            }
            #pragma unroll
            for (int nf = 0; nf < 4; ++nf) {
                int br = wc * 64 + nf * 16 + frow;
                b0f[nf] = *(const bf16x8*)&sB0[cur][br][h * 32 + fsel * 8];
                b1f[nf] = *(const bf16x8*)&sB1[cur][br][h * 32 + fsel * 8];
            }
            #pragma unroll
            for (int nf = 0; nf < 4; ++nf)
                #pragma unroll
                for (int mf = 0; mf < 4; ++mf) {
                    accg[mf][nf] = __builtin_amdgcn_mfma_f32_16x16x32_bf16(af[mf], b0f[nf], accg[mf][nf], 0, 0, 0);
                    accu[mf][nf] = __builtin_amdgcn_mfma_f32_16x16x32_bf16(af[mf], b1f[nf], accu[mf][nf], 0, 0, 0);
                }
        }
        if (kt + 1 < KT) {
            short* d0 = &sB0[nxt][brow][bq * 16];
            *(bf16x8*)d0       = pack8(rb0[0], rb0[1]);
            *(bf16x8*)(d0 + 8) = pack8(rb0[2], rb0[3]);
            short* d1 = &sB1[nxt][brow][bq * 16];
            *(bf16x8*)d1       = pack8(rb1[0], rb1[1]);
            *(bf16x8*)(d1 + 8) = pack8(rb1[2], rb1[3]);
        }
        __syncthreads();
    }

    const int r4 = fsel * 4;
    #pragma unroll
    for (int mf = 0; mf < 4; ++mf)
        #pragma unroll
        for (int nf = 0; nf < 4; ++nf)
            #pragma unroll
            for (int j = 0; j < 4; ++j) {
                int rr = wr * 64 + mf * 16 + r4 + j;
                if (rr < rows) {
                    float g = accg[mf][nf][j];
                    float u = accu[mf][nf][j];
                    float sig = 1.f / (1.f + __expf(-g));
                    float v = g * sig * u * sPw[rr];
                    int col = n0 + wc * 64 + nf * 16 + frow;
                    Hbuf[(size_t)(row0 + rr) * I_DIM + col] = f2bf(v);
                }
            }
}

__global__ __launch_bounds__(256, 2) void gemm2_kernel(
    const short* __restrict__ Hbuf, const float* __restrict__ Wo,
    const int* __restrict__ pair_token,
    const int* __restrict__ tile_expert, const int* __restrict__ tile_row0,
    const int* __restrict__ tile_rows,
    float* __restrict__ out)
{
    const int tile = blockIdx.x;
    const int rows = tile_rows[tile];
    if (rows == 0) return;
    const int e    = tile_expert[tile];
    const int row0 = tile_row0[tile];
    const int n0   = blockIdx.y * 256;

    __shared__ short sA[BM][BK + 8];
    __shared__ short sB[256][BK + 8];
    __shared__ int   sTok[BM];

    const int tid = threadIdx.x;
    if (tid < BM) sTok[tid] = pair_token[row0 + min(tid, rows - 1)];
    __syncthreads();

    const int srow  = tid >> 1;
    const int shalf = tid & 1;

    const short* aptr = Hbuf + (size_t)(row0 + min(srow, rows - 1)) * I_DIM + shalf * 16;
    const float* bptrA = Wo + ((size_t)e * H_DIM + (n0 + srow))       * I_DIM + shalf * 16;
    const float* bptrB = Wo + ((size_t)e * H_DIM + (n0 + srow + 128)) * I_DIM + shalf * 16;

    bf16x8 ra[2];
    f32x4v rbA[4], rbB[4];
    f32x4v acc[4][8];
    #pragma unroll
    for (int mf = 0; mf < 4; ++mf)
        #pragma unroll
        for (int nf = 0; nf < 8; ++nf) acc[mf][nf] = (f32x4v)0.f;

    const int lane = tid & 63;
    const int wid  = tid >> 6;
    const int wr   = wid >> 1;
    const int wc   = wid & 1;
    const int frow = lane & 15;
    const int fk   = (lane >> 4) * 8;

    ra[0] = *(const bf16x8*)(aptr);
    ra[1] = *(const bf16x8*)(aptr + 8);
    #pragma unroll
    for (int i = 0; i < 4; ++i) { rbA[i] = *(const f32x4v*)(bptrA + i * 4); rbB[i] = *(const f32x4v*)(bptrB + i * 4); }

    const int KT = I_DIM / BK;
    for (int kt = 0; kt < KT; ++kt) {
        __syncthreads();
        *(bf16x8*)&sA[srow][shalf * 16]           = ra[0];
        *(bf16x8*)&sA[srow][shalf * 16 + 8]       = ra[1];
        *(bf16x8*)&sB[srow][shalf * 16]           = pack8(rbA[0], rbA[1]);
        *(bf16x8*)&sB[srow][shalf * 16 + 8]       = pack8(rbA[2], rbA[3]);
        *(bf16x8*)&sB[srow + 128][shalf * 16]     = pack8(rbB[0], rbB[1]);
        *(bf16x8*)&sB[srow + 128][shalf * 16 + 8] = pack8(rbB[2], rbB[3]);
        __syncthreads();

        if (kt + 1 < KT) {
            const int k = (kt + 1) * BK;
            ra[0] = *(const bf16x8*)(aptr + k);
            ra[1] = *(const bf16x8*)(aptr + k + 8);
            #pragma unroll
            for (int i = 0; i < 4; ++i) { rbA[i] = *(const f32x4v*)(bptrA + k + i * 4); rbB[i] = *(const f32x4v*)(bptrB + k + i * 4); }
        }

        bf16x8 af[4];
        #pragma unroll
        for (int mf = 0; mf < 4; ++mf)
            af[mf] = *(const bf16x8*)&sA[wr * 64 + mf * 16 + frow][fk];
        #pragma unroll
        for (int nf = 0; nf < 8; ++nf) {
            bf16x8 bfv = *(const bf16x8*)&sB[wc * 128 + nf * 16 + frow][fk];
            #pragma unroll
            for (int mf = 0; mf < 4; ++mf)
                acc[mf][nf] = __builtin_amdgcn_mfma_f32_16x16x32_bf16(af[mf], bfv, acc[mf][nf], 0, 0, 0);
        }
    }

    const int r4 = (lane >> 4) * 4;
    #pragma unroll
    for (int mf = 0; mf < 4; ++mf)
        #pragma unroll
        for (int nf = 0; nf < 8; ++nf)
            #pragma unroll
            for (int j = 0; j < 4; ++j) {
                int rr = wr * 64 + mf * 16 + r4 + j;
                if (rr < rows) {
                    int col = n0 + wc * 128 + nf * 16 + (lane & 15);
                    atomicAdd(out + (size_t)sTok[rr] * H_DIM + col, acc[mf][nf][j]);
                }
            }
}

// ---------------- launch ----------------
extern "C" void kernel_launch(void* const* d_in, const int* in_sizes, int n_in,
                              void* d_out, int out_size, void* d_ws, size_t ws_size,
                              hipStream_t stream)
{
    (void)in_sizes; (void)n_in;
    const float* X     = (const float*)d_in[0];
    const float* topw  = (const float*)d_in[1];
    const int*   topid = (const int*)d_in[2];
    const float* Wi0   = (const float*)d_in[3];
    const float* Wi1   = (const float*)d_in[4];
    const float* Wo    = (const float*)d_in[5];
    float* out = (float*)d_out;

    char* ws = (char*)d_ws;
    int*   pair_token  = (int*)ws;
    float* pair_w      = (float*)(ws + NPAIR * 4);
    int*   tile_expert = (int*)(ws + NPAIR * 8);
    int*   tile_row0   = tile_expert + MAXT;
    int*   tile_rows   = tile_row0 + MAXT;
    int*   t1_expert   = tile_rows + MAXT;
    int*   t1_row0     = t1_expert + MAXT1;
    int*   t1_rows     = t1_row0 + MAXT1;

    route_kernel<<<1, 256, 0, stream>>>(topid, topw, pair_token, pair_w,
                                        tile_expert, tile_row0, tile_rows,
                                        t1_expert, t1_row0, t1_rows);

    if (ws_size >= NEED_NEW) {
        short* Ht  = (short*)(ws + HT_OFF);
        short* W0t = (short*)(ws + W0_OFF);
        short* W1t = (short*)(ws + W1_OFF);
        short* At  = (short*)(ws + AT_OFF);
        short* Wot = W0t;   // overlays W0t after gemm1b

        hipMemsetAsync(d_out, 0, (size_t)out_size * sizeof(float), stream);

        aprep_kernel<<<2560, 256, 0, stream>>>(X, pair_token, t1_row0, t1_rows, At);
        wprep_kernel<<<4096, 256, 0, stream>>>(Wi0, W0t);
        wprep_kernel<<<4096, 256, 0, stream>>>(Wi1, W1t);

        gemm1b_kernel<<<MAXT1 * 16, 512, 0, stream>>>(
            At, W0t, W1t, pair_w, t1_expert, t1_row0, t1_rows, Ht);

        woprep_kernel<<<4096, 256, 0, stream>>>(Wo, Wot);

        gemm2b_kernel<<<MAXT1 * 16, 512, 0, stream>>>(
            Ht, Wot, pair_token, t1_expert, t1_row0, t1_rows, out);
    } else {
        short* Hbuf = (short*)(ws + (1 << 20));
        short* Xbf  = (short*)d_out;

        cvt_kernel<<<T_TOK * H_DIM / (256 * 8), 256, 0, stream>>>(X, Xbf);

        gemm1_kernel<<<dim3(MAXT1, I_DIM / BN1), 512, 0, stream>>>(
            Xbf, Wi0, Wi1, pair_token, pair_w, t1_expert, t1_row0, t1_rows, Hbuf);

        hipMemsetAsync(d_out, 0, (size_t)out_size * sizeof(float), stream);

        gemm2_kernel<<<dim3(MAXT, H_DIM / 256), 256, 0, stream>>>(
            Hbuf, Wo, pair_token, tile_expert, tile_row0, tile_rows, out);
    }
}

// Round 8
// 1060.528 us; speedup vs baseline: 5.3736x; 1.0917x over previous
//
#include <hip/hip_runtime.h>
#include <hip/hip_bf16.h>

#define T_TOK 4096
#define H_DIM 4096
#define I_DIM 2048
#define N_EXP 8
#define TOPK  2
#define NPAIR (T_TOK*TOPK)          // 8192
#define BM    128                   // fallback gemm2 M-tile
#define BK    32
#define MAXT  (NPAIR/BM + N_EXP)    // 72
#define BM1   256
#define BN1   128
#define MAXT1 (NPAIR/BM1 + N_EXP)   // 40

// ---- tiled-workspace offsets (bytes) ----
#define HT_OFF   ((size_t)1 << 20)
#define W0_OFF   ((size_t)45 << 20)                 // Wot (gemm2 weights)
#define W1_OFF   (W0_OFF + 134217728ull)
#define AT_OFF   (W1_OFF + 134217728ull)
#define NEED_NEW (AT_OFF + 83886080ull)             // ~381 MB (unchanged, proven)

typedef __attribute__((ext_vector_type(8))) short  bf16x8;
typedef __attribute__((ext_vector_type(4))) float  f32x4v;

__device__ __forceinline__ short f2bf(float f) {
    __hip_bfloat16 h = __float2bfloat16(f);
    return __builtin_bit_cast(short, h);
}

__device__ __forceinline__ bf16x8 pack8(f32x4v a, f32x4v b) {
    bf16x8 r;
    r[0]=f2bf(a[0]); r[1]=f2bf(a[1]); r[2]=f2bf(a[2]); r[3]=f2bf(a[3]);
    r[4]=f2bf(b[0]); r[5]=f2bf(b[1]); r[6]=f2bf(b[2]); r[7]=f2bf(b[3]);
    return r;
}

__device__ __forceinline__ void load_lds16(const short* g, short* l) {
    __builtin_amdgcn_global_load_lds(
        (const __attribute__((address_space(1))) void*)g,
        (__attribute__((address_space(3))) void*)l, 16, 0, 0);
}

// ---------------- fp32 -> bf16 plain (fallback X path) ----------------
__global__ void cvt_kernel(const float* __restrict__ X, short* __restrict__ Xbf) {
    const size_t i = ((size_t)blockIdx.x * 256 + threadIdx.x) * 8;
    f32x4v a = *(const f32x4v*)(X + i);
    f32x4v b = *(const f32x4v*)(X + i + 4);
    *(bf16x8*)(Xbf + i) = pack8(a, b);
}

// ---------------- routing ----------------
__global__ void route_kernel(const int* __restrict__ ids, const float* __restrict__ wts,
                             int* __restrict__ pair_token, float* __restrict__ pair_w,
                             int* __restrict__ tile_expert, int* __restrict__ tile_row0,
                             int* __restrict__ tile_rows,
                             int* __restrict__ t1_expert, int* __restrict__ t1_row0,
                             int* __restrict__ t1_rows)
{
    __shared__ int scn[256][N_EXP];
    const int tid = threadIdx.x;
    const int PPT = NPAIR / 256;
    const int base = tid * PPT;

    int c[N_EXP], orig[N_EXP];
    #pragma unroll
    for (int e = 0; e < N_EXP; ++e) c[e] = 0;
    for (int p = 0; p < PPT; ++p) c[ids[base + p]]++;
    #pragma unroll
    for (int e = 0; e < N_EXP; ++e) { orig[e] = c[e]; scn[tid][e] = c[e]; }
    __syncthreads();

    for (int off = 1; off < 256; off <<= 1) {
        int add[N_EXP];
        #pragma unroll
        for (int e = 0; e < N_EXP; ++e) add[e] = (tid >= off) ? scn[tid - off][e] : 0;
        __syncthreads();
        #pragma unroll
        for (int e = 0; e < N_EXP; ++e) { c[e] += add[e]; scn[tid][e] = c[e]; }
        __syncthreads();
    }

    int segs[N_EXP + 1];
    {
        int run = 0;
        #pragma unroll
        for (int e = 0; e < N_EXP; ++e) { segs[e] = run; run += scn[255][e]; }
        segs[N_EXP] = run;
    }
    int pos[N_EXP];
    #pragma unroll
    for (int e = 0; e < N_EXP; ++e) pos[e] = segs[e] + c[e] - orig[e];

    for (int p = 0; p < PPT; ++p) {
        int pp = base + p;
        int e = ids[pp];
        int q = pos[e]++;
        pair_token[q] = pp / TOPK;
        pair_w[q]     = wts[pp];
    }

    if (tid == 0) {
        int t = 0;
        for (int e = 0; e < N_EXP; ++e) {
            int s = segs[e], en = segs[e + 1];
            for (int r = s; r < en; r += BM) {
                tile_expert[t] = e; tile_row0[t] = r; tile_rows[t] = min(BM, en - r); ++t;
            }
        }
        for (; t < MAXT; ++t) { tile_expert[t] = 0; tile_row0[t] = 0; tile_rows[t] = 0; }

        t = 0;
        for (int e = 0; e < N_EXP; ++e) {
            int s = segs[e], en = segs[e + 1];
            for (int r = s; r < en; r += BM1) {
                t1_expert[t] = e; t1_row0[t] = r; t1_rows[t] = min(BM1, en - r); ++t;
            }
        }
        for (; t < MAXT1; ++t) { t1_expert[t] = 0; t1_row0[t] = 0; t1_rows[t] = 0; }
    }
}

// ================= coalesced LDS-transpose preps (aprep + woprep only) =================
#define PRP 132

// Wo (E,H,I) fp32 -> Wot [e][hb][kt 64][q 4][r 256][x 8]
__global__ __launch_bounds__(256) void woprep_kernel(const float* __restrict__ W, short* __restrict__ Wt) {
    const int bid = blockIdx.x;          // 8 * 16 * 2 * 16 = 4096
    const int e   = bid >> 9;
    const int hb  = (bid >> 5) & 15;
    const int rh  = (bid >> 4) & 1;
    const int ktg = bid & 15;
    __shared__ short lds[128][PRP];
    const int tid = threadIdx.x;
    const float* src0 = W + ((size_t)(e * 4096 + hb * 256 + rh * 128)) * 2048 + ktg * 128;
    #pragma unroll
    for (int it = 0; it < 8; ++it) {
        int r  = it * 16 + (tid >> 4);
        int hc = (tid & 15) * 8;
        const float* s = src0 + (size_t)r * 2048 + hc;
        f32x4v a = *(const f32x4v*)s;
        f32x4v b = *(const f32x4v*)(s + 4);
        *(bf16x8*)&lds[r][hc] = pack8(a, b);
    }
    __syncthreads();
    short* dst = Wt + (((size_t)(e * 16 + hb) * 64 + ktg * 4) * 8192) + rh * 1024;
    #pragma unroll
    for (int it = 0; it < 8; ++it) {
        int off = it * 2048 + tid * 8;
        int ktl = off >> 12;
        int q   = (off >> 10) & 3;
        int rl  = (off >> 3) & 127;
        bf16x8 v = *(const bf16x8*)&lds[rl][ktl * 32 + q * 8];
        *(bf16x8*)(dst + (size_t)ktl * 8192 + q * 2048 + rl * 8) = v;
    }
}

// X gather -> At [tile][kt 128][q 4][r 256][x 8]
__global__ __launch_bounds__(256) void aprep_kernel(const float* __restrict__ X,
                             const int* __restrict__ pair_token,
                             const int* __restrict__ t1_row0, const int* __restrict__ t1_rows,
                             short* __restrict__ At) {
    const int bid  = blockIdx.x;         // 40 * 2 * 32 = 2560
    const int tile = bid >> 6;
    const int rh   = (bid >> 5) & 1;
    const int ktg  = bid & 31;
    const int rows = t1_rows[tile];
    if (rows == 0) return;
    const int row0 = t1_row0[tile];
    __shared__ short lds[128][PRP];
    const int tid = threadIdx.x;
    #pragma unroll
    for (int it = 0; it < 8; ++it) {
        int r  = it * 16 + (tid >> 4);
        int hc = (tid & 15) * 8;
        int tok = pair_token[row0 + min(rh * 128 + r, rows - 1)];
        const float* s = X + (size_t)tok * 4096 + ktg * 128 + hc;
        f32x4v a = *(const f32x4v*)s;
        f32x4v b = *(const f32x4v*)(s + 4);
        *(bf16x8*)&lds[r][hc] = pack8(a, b);
    }
    __syncthreads();
    short* dst = At + (((size_t)tile * 128 + ktg * 4) * 8192) + rh * 1024;
    #pragma unroll
    for (int it = 0; it < 8; ++it) {
        int off = it * 2048 + tid * 8;
        int ktl = off >> 12;
        int q   = (off >> 10) & 3;
        int rl  = (off >> 3) & 127;
        bf16x8 v = *(const bf16x8*)&lds[rl][ktl * 32 + q * 8];
        *(bf16x8*)(dst + (size_t)ktl * 8192 + q * 2048 + rl * 8) = v;
    }
}

// ================= GEMM1: fine 2-phase interleave, A via gload_lds ring, B fp32 reg-staged =================
// LDS stage (16B slots): A [0..1023]=q*256+r ; B0 [1024..1535]=q*128+r ; B1 [1536..2047]

__global__ __launch_bounds__(512, 2) void gemm1b_kernel(
    const short* __restrict__ At,       // [40][128][4][256][8] bf16 tiled
    const float* __restrict__ Wi0,      // [E][I][H] fp32 (no prep!)
    const float* __restrict__ Wi1,
    const float* __restrict__ pair_w,
    const int* __restrict__ t1_expert, const int* __restrict__ t1_row0,
    const int* __restrict__ t1_rows,
    short* __restrict__ Ht)             // [40][64][4][256][8]
{
    const int b    = blockIdx.x;
    const int xcd  = b & 7;
    const int i    = b >> 3;
    const int tile  = xcd * 5 + (i >> 4);
    const int n0idx = i & 15;
    const int rows = t1_rows[tile];
    if (rows == 0) return;
    const int e    = t1_expert[tile];
    const int row0 = t1_row0[tile];
    const int n0   = n0idx * BN1;

    __shared__ short stg[4][16384];      // 128 KB, 4-ring (A 3-deep; B written 1-ahead)
    __shared__ float sPw[BM1];

    const int tid  = threadIdx.x;
    const int lane = tid & 63;
    const int w    = tid >> 6;
    const int wof  = w * 512;

    if (tid < BM1) sPw[tid] = (tid < rows) ? pair_w[row0 + tid] : 0.f;
    __syncthreads();

    const short* aT = At + (size_t)tile * 1048576 + (size_t)tid * 8;

    // B fp32 direct: thread -> row tid>>2 (0..127), col-chunk (tid&3)*8
    const int brow = tid >> 2;
    const int bq   = tid & 3;
    const float* b0p = Wi0 + ((size_t)e * I_DIM + n0 + brow) * H_DIM + bq * 8;
    const float* b1p = Wi1 + ((size_t)e * I_DIM + n0 + brow) * H_DIM + bq * 8;
    const int slotB0 = (1024 + bq * 128 + brow) * 8;   // short offsets
    const int slotB1 = (1536 + bq * 128 + brow) * 8;

    const int wr = w >> 1, wc = w & 1;
    const int frow = lane & 15, fsel = lane >> 4;

    f32x4v accg[4][4], accu[4][4];
    #pragma unroll
    for (int mf = 0; mf < 4; ++mf)
        #pragma unroll
        for (int nf = 0; nf < 4; ++nf) { accg[mf][nf] = (f32x4v)0.f; accu[mf][nf] = (f32x4v)0.f; }

    f32x4v rb0a, rb0b, rb1a, rb1b;

#define STAGEA(s, kt) do { \
        short* st_ = &stg[s][0] + wof; \
        const size_t ko_ = (size_t)(kt); \
        load_lds16(aT + ko_ * 8192,        st_); \
        load_lds16(aT + ko_ * 8192 + 4096, st_ + 4096); \
    } while (0)

#define LOADB(kt) do { \
        const float* p0_ = b0p + (size_t)(kt) * 32; \
        const float* p1_ = b1p + (size_t)(kt) * 32; \
        rb0a = *(const f32x4v*)p0_; rb0b = *(const f32x4v*)(p0_ + 4); \
        rb1a = *(const f32x4v*)p1_; rb1b = *(const f32x4v*)(p1_ + 4); \
    } while (0)

#define WRITEB(s) do { \
        short* st_ = &stg[s][0]; \
        *(bf16x8*)(st_ + slotB0) = pack8(rb0a, rb0b); \
        *(bf16x8*)(st_ + slotB1) = pack8(rb1a, rb1b); \
    } while (0)

    // prologue: A(0..2) in flight, B(0) loaded+written
    STAGEA(0, 0); STAGEA(1, 1); STAGEA(2, 2);
    LOADB(0);
    asm volatile("s_waitcnt vmcnt(0)" ::: "memory");
    WRITEB(0);
    asm volatile("s_waitcnt lgkmcnt(0)" ::: "memory");
    __builtin_amdgcn_s_barrier();
    __builtin_amdgcn_sched_barrier(0);

    const int KT = H_DIM / 32;   // 128
    for (int kt = 0; kt < KT; ++kt) {
        const short* st = &stg[kt & 3][0];

        // ---- phase 1: issue B(kt+1) loads; ds_read A-frags + B0-frags; MFMA gate ----
        if (kt + 1 < KT) LOADB(kt + 1);
        bf16x8 af[4], b0f[4];
        #pragma unroll
        for (int mf = 0; mf < 4; ++mf)
            af[mf] = *(const bf16x8*)(st + (fsel * 256 + wr * 64 + mf * 16 + frow) * 8);
        #pragma unroll
        for (int nf = 0; nf < 4; ++nf)
            b0f[nf] = *(const bf16x8*)(st + (1024 + fsel * 128 + wc * 64 + nf * 16 + frow) * 8);
        __builtin_amdgcn_s_barrier();
        asm volatile("s_waitcnt lgkmcnt(0)" ::: "memory");
        __builtin_amdgcn_sched_barrier(0);
        __builtin_amdgcn_s_setprio(1);
        #pragma unroll
        for (int nf = 0; nf < 4; ++nf)
            #pragma unroll
            for (int mf = 0; mf < 4; ++mf)
                accg[mf][nf] = __builtin_amdgcn_mfma_f32_16x16x32_bf16(af[mf], b0f[nf], accg[mf][nf], 0, 0, 0);
        __builtin_amdgcn_s_setprio(0);

        // ---- phase 2: issue A(kt+3) gloads; ds_read B1-frags; MFMA up ----
        if (kt + 3 < KT) STAGEA((kt + 3) & 3, kt + 3);
        bf16x8 b1f[4];
        #pragma unroll
        for (int nf = 0; nf < 4; ++nf)
            b1f[nf] = *(const bf16x8*)(st + (1536 + fsel * 128 + wc * 64 + nf * 16 + frow) * 8);
        __builtin_amdgcn_s_barrier();
        asm volatile("s_waitcnt lgkmcnt(0)" ::: "memory");
        __builtin_amdgcn_sched_barrier(0);
        __builtin_amdgcn_s_setprio(1);
        #pragma unroll
        for (int nf = 0; nf < 4; ++nf)
            #pragma unroll
            for (int mf = 0; mf < 4; ++mf)
                accu[mf][nf] = __builtin_amdgcn_mfma_f32_16x16x32_bf16(af[mf], b1f[nf], accu[mf][nf], 0, 0, 0);
        __builtin_amdgcn_s_setprio(0);
        __builtin_amdgcn_sched_barrier(0);

        // ---- commit: counted vmcnt (never 0 mid-loop), write B(kt+1), publish ----
        if (kt + 1 < KT) {
            if (kt + 3 < KT) asm volatile("s_waitcnt vmcnt(2)" ::: "memory");
            else             asm volatile("s_waitcnt vmcnt(0)" ::: "memory");
            WRITEB((kt + 1) & 3);
            asm volatile("s_waitcnt lgkmcnt(0)" ::: "memory");
            __builtin_amdgcn_s_barrier();
            __builtin_amdgcn_sched_barrier(0);
        }
    }
#undef STAGEA
#undef LOADB
#undef WRITEB

    // epilogue: silu(g)*u*pw -> Ht (tiled layout)
    const int r4 = fsel * 4;
    #pragma unroll
    for (int mf = 0; mf < 4; ++mf)
        #pragma unroll
        for (int nf = 0; nf < 4; ++nf) {
            const int col = n0 + wc * 64 + nf * 16 + frow;
            const size_t cbase = (((size_t)tile * 64 + (col >> 5)) * 8192)
                               + (size_t)((col >> 3) & 3) * 2048 + (col & 7);
            #pragma unroll
            for (int j = 0; j < 4; ++j) {
                int rr = wr * 64 + mf * 16 + r4 + j;
                if (rr < rows) {
                    float g = accg[mf][nf][j];
                    float u = accu[mf][nf][j];
                    float sig = 1.f / (1.f + __expf(-g));
                    Ht[cbase + (size_t)rr * 8] = f2bf(g * sig * u * sPw[rr]);
                }
            }
        }
}

// ================= GEMM2 (UNCHANGED from R7 — control) =================
__global__ __launch_bounds__(512, 2) void gemm2b_kernel(
    const short* __restrict__ Ht,       // [40][64][4][256][8]
    const short* __restrict__ Wot,      // [E][16][64][4][256][8]
    const int* __restrict__ pair_token,
    const int* __restrict__ t1_expert, const int* __restrict__ t1_row0,
    const int* __restrict__ t1_rows,
    float* __restrict__ out)            // [T][H]
{
    const int b    = blockIdx.x;
    const int xcd  = b & 7;
    const int i    = b >> 3;
    const int tile  = xcd * 5 + (i >> 4);
    const int n0idx = i & 15;            // over H/256
    const int rows = t1_rows[tile];
    if (rows == 0) return;
    const int e    = t1_expert[tile];
    const int row0 = t1_row0[tile];
    const int n0   = n0idx * 256;

    __shared__ short stg[4][16384];      // 128 KB
    __shared__ int   sTok[BM1];

    const int tid  = threadIdx.x;
    const int lane = tid & 63;
    const int w    = tid >> 6;
    const int wof  = w * 512;

    if (tid < BM1) sTok[tid] = pair_token[row0 + min(tid, rows - 1)];
    __syncthreads();

    const short* aT = Ht  + (size_t)tile * 524288 + (size_t)tid * 8;
    const short* bT = Wot + ((size_t)e * 16 + n0idx) * 524288 + (size_t)tid * 8;

    const int wr = w >> 1, wc = w & 1;
    const int frow = lane & 15, fsel = lane >> 4;

    f32x4v acc[4][8];
    #pragma unroll
    for (int mf = 0; mf < 4; ++mf)
        #pragma unroll
        for (int nf = 0; nf < 8; ++nf) acc[mf][nf] = (f32x4v)0.f;

#define STAGE2(s, kt) do { \
        short* st_ = &stg[s][0] + wof; \
        const size_t ko_ = (size_t)(kt); \
        load_lds16(aT + ko_ * 8192,        st_); \
        load_lds16(aT + ko_ * 8192 + 4096, st_ + 4096); \
        load_lds16(bT + ko_ * 8192,        st_ + 8192); \
        load_lds16(bT + ko_ * 8192 + 4096, st_ + 12288); \
    } while (0)

#define COMPUTE2(s) do { \
        const short* st_ = &stg[s][0]; \
        bf16x8 af[4], bf_[8]; \
        _Pragma("unroll") \
        for (int mf = 0; mf < 4; ++mf) \
            af[mf] = *(const bf16x8*)(st_ + (fsel * 256 + wr * 64 + mf * 16 + frow) * 8); \
        _Pragma("unroll") \
        for (int nf = 0; nf < 8; ++nf) \
            bf_[nf] = *(const bf16x8*)(st_ + (1024 + fsel * 256 + wc * 128 + nf * 16 + frow) * 8); \
        __builtin_amdgcn_s_setprio(1); \
        _Pragma("unroll") \
        for (int nf = 0; nf < 8; ++nf) \
            _Pragma("unroll") \
            for (int mf = 0; mf < 4; ++mf) \
                acc[mf][nf] = __builtin_amdgcn_mfma_f32_16x16x32_bf16(af[mf], bf_[nf], acc[mf][nf], 0, 0, 0); \
        __builtin_amdgcn_s_setprio(0); \
    } while (0)

    STAGE2(0, 0); STAGE2(1, 1); STAGE2(2, 2);
    asm volatile("s_waitcnt vmcnt(8)" ::: "memory");
    __builtin_amdgcn_s_barrier();
    __builtin_amdgcn_sched_barrier(0);

    const int KT = I_DIM / 32;   // 64
    for (int kt = 0; kt < KT; ++kt) {
        const int cur = kt & 3;
        if (kt + 3 < KT) STAGE2((kt + 3) & 3, kt + 3);
        COMPUTE2(cur);
        if (kt + 1 < KT) {
            __builtin_amdgcn_sched_barrier(0);
            if (kt + 3 < KT)      asm volatile("s_waitcnt vmcnt(8)" ::: "memory");
            else if (kt + 2 < KT) asm volatile("s_waitcnt vmcnt(4)" ::: "memory");
            else                  asm volatile("s_waitcnt vmcnt(0)" ::: "memory");
            __builtin_amdgcn_s_barrier();
            __builtin_amdgcn_sched_barrier(0);
        }
    }
#undef STAGE2
#undef COMPUTE2

    const int r4 = fsel * 4;
    #pragma unroll
    for (int mf = 0; mf < 4; ++mf)
        #pragma unroll
        for (int nf = 0; nf < 8; ++nf)
            #pragma unroll
            for (int j = 0; j < 4; ++j) {
                int rr = wr * 64 + mf * 16 + r4 + j;
                if (rr < rows) {
                    int col = n0 + wc * 128 + nf * 16 + frow;
                    atomicAdd(out + (size_t)sTok[rr] * H_DIM + col, acc[mf][nf][j]);
                }
            }
}

// ================= FALLBACK PATH (R3) =================
__global__ __launch_bounds__(512, 2) void gemm1_kernel(
    const short* __restrict__ Xbf, const float* __restrict__ Wi0, const float* __restrict__ Wi1,
    const int* __restrict__ pair_token, const float* __restrict__ pair_w,
    const int* __restrict__ t1_expert, const int* __restrict__ t1_row0, const int* __restrict__ t1_rows,
    short* __restrict__ Hbuf)
{
    const int tile = blockIdx.x;
    const int rows = t1_rows[tile];
    if (rows == 0) return;
    const int e    = t1_expert[tile];
    const int row0 = t1_row0[tile];
    const int n0   = blockIdx.y * BN1;

    __shared__ short sA [2][BM1][64];
    __shared__ short sB0[2][BN1][64 + 8];
    __shared__ short sB1[2][BN1][64 + 8];
    __shared__ int   sTok[BM1];
    __shared__ float sPw [BM1];

    const int tid  = threadIdx.x;
    const int lane = tid & 63;
    const int w    = tid >> 6;

    if (tid < BM1) {
        int tr = min(tid, rows - 1);
        sTok[tid] = pair_token[row0 + tr];
        sPw[tid]  = (tid < rows) ? pair_w[row0 + tid] : 0.f;
    }
    __syncthreads();

    const short* aSrc[4];
    #pragma unroll
    for (int i = 0; i < 4; ++i) {
        int r = w * 32 + i * 8 + (lane >> 3);
        int j = lane & 7;
        aSrc[i] = Xbf + (size_t)sTok[r] * H_DIM + ((j ^ (r & 7)) * 8);
    }

    const int brow = tid >> 2;
    const int bq   = tid & 3;
    const size_t wboff = ((size_t)e * I_DIM + (n0 + brow)) * H_DIM + bq * 16;
    const float* b0p = Wi0 + wboff;
    const float* b1p = Wi1 + wboff;

    const int wr   = w >> 1;
    const int wc   = w & 1;
    const int frow = lane & 15;
    const int fsel = lane >> 4;

    f32x4v accg[4][4], accu[4][4];
    #pragma unroll
    for (int mf = 0; mf < 4; ++mf)
        #pragma unroll
        for (int nf = 0; nf < 4; ++nf) { accg[mf][nf] = (f32x4v)0.f; accu[mf][nf] = (f32x4v)0.f; }

    f32x4v rb0[4], rb1[4];

    #pragma unroll
    for (int i = 0; i < 4; ++i)
        load_lds16(aSrc[i], &sA[0][w * 32 + i * 8][0]);
    #pragma unroll
    for (int i = 0; i < 4; ++i) { rb0[i] = *(const f32x4v*)(b0p + i * 4); rb1[i] = *(const f32x4v*)(b1p + i * 4); }
    {
        short* d0 = &sB0[0][brow][bq * 16];
        *(bf16x8*)d0       = pack8(rb0[0], rb0[1]);
        *(bf16x8*)(d0 + 8) = pack8(rb0[2], rb0[3]);
        short* d1 = &sB1[0][brow][bq * 16];
        *(bf16x8*)d1       = pack8(rb1[0], rb1[1]);
        *(bf16x8*)(d1 + 8) = pack8(rb1[2], rb1[3]);
    }
    __syncthreads();

    const int KT = H_DIM / 64;
    for (int kt = 0; kt < KT; ++kt) {
        const int cur = kt & 1, nxt = cur ^ 1;
        if (kt + 1 < KT) {
            #pragma unroll
            for (int i = 0; i < 4; ++i)
                load_lds16(aSrc[i] + (kt + 1) * 64, &sA[nxt][w * 32 + i * 8][0]);
            const float* p0 = b0p + (kt + 1) * 64;
            const float* p1 = b1p + (kt + 1) * 64;
            #pragma unroll
            for (int i = 0; i < 4; ++i) { rb0[i] = *(const f32x4v*)(p0 + i * 4); rb1[i] = *(const f32x4v*)(p1 + i * 4); }
        }
        #pragma unroll
        for (int h = 0; h < 2; ++h) {
            bf16x8 af[4], b0f[4], b1f[4];
            #pragma unroll
            for (int mf = 0; mf < 4; ++mf) {
                int ar = wr * 64 + mf * 16 + frow;
                int c  = (h * 4 + fsel) ^ (ar & 7);
                af[mf] = *(const bf16x8*)((const char*)&sA[cur][0][0] + ar * 128 + c * 16);
            }
            #pragma unroll
            for (int nf = 0; nf < 4; ++nf) {
                int br = wc * 64 + nf * 16 + frow;
                b0f[nf] = *(const bf16x8*)&sB0[cur][br][h * 32 + fsel * 8];
                b1f[nf] = *(const bf16x8*)&sB1[cur][br][h * 32 + fsel * 8];
            }
            #pragma unroll
            for (int nf = 0; nf < 4; ++nf)
                #pragma unroll
                for (int mf = 0; mf < 4; ++mf) {
                    accg[mf][nf] = __builtin_amdgcn_mfma_f32_16x16x32_bf16(af[mf], b0f[nf], accg[mf][nf], 0, 0, 0);
                    accu[mf][nf] = __builtin_amdgcn_mfma_f32_16x16x32_bf16(af[mf], b1f[nf], accu[mf][nf], 0, 0, 0);
                }
        }
        if (kt + 1 < KT) {
            short* d0 = &sB0[nxt][brow][bq * 16];
            *(bf16x8*)d0       = pack8(rb0[0], rb0[1]);
            *(bf16x8*)(d0 + 8) = pack8(rb0[2], rb0[3]);
            short* d1 = &sB1[nxt][brow][bq * 16];
            *(bf16x8*)d1       = pack8(rb1[0], rb1[1]);
            *(bf16x8*)(d1 + 8) = pack8(rb1[2], rb1[3]);
        }
        __syncthreads();
    }

    const int r4 = fsel * 4;
    #pragma unroll
    for (int mf = 0; mf < 4; ++mf)
        #pragma unroll
        for (int nf = 0; nf < 4; ++nf)
            #pragma unroll
            for (int j = 0; j < 4; ++j) {
                int rr = wr * 64 + mf * 16 + r4 + j;
                if (rr < rows) {
                    float g = accg[mf][nf][j];
                    float u = accu[mf][nf][j];
                    float sig = 1.f / (1.f + __expf(-g));
                    float v = g * sig * u * sPw[rr];
                    int col = n0 + wc * 64 + nf * 16 + frow;
                    Hbuf[(size_t)(row0 + rr) * I_DIM + col] = f2bf(v);
                }
            }
}

__global__ __launch_bounds__(256, 2) void gemm2_kernel(
    const short* __restrict__ Hbuf, const float* __restrict__ Wo,
    const int* __restrict__ pair_token,
    const int* __restrict__ tile_expert, const int* __restrict__ tile_row0,
    const int* __restrict__ tile_rows,
    float* __restrict__ out)
{
    const int tile = blockIdx.x;
    const int rows = tile_rows[tile];
    if (rows == 0) return;
    const int e    = tile_expert[tile];
    const int row0 = tile_row0[tile];
    const int n0   = blockIdx.y * 256;

    __shared__ short sA[BM][BK + 8];
    __shared__ short sB[256][BK + 8];
    __shared__ int   sTok[BM];

    const int tid = threadIdx.x;
    if (tid < BM) sTok[tid] = pair_token[row0 + min(tid, rows - 1)];
    __syncthreads();

    const int srow  = tid >> 1;
    const int shalf = tid & 1;

    const short* aptr = Hbuf + (size_t)(row0 + min(srow, rows - 1)) * I_DIM + shalf * 16;
    const float* bptrA = Wo + ((size_t)e * H_DIM + (n0 + srow))       * I_DIM + shalf * 16;
    const float* bptrB = Wo + ((size_t)e * H_DIM + (n0 + srow + 128)) * I_DIM + shalf * 16;

    bf16x8 ra[2];
    f32x4v rbA[4], rbB[4];
    f32x4v acc[4][8];
    #pragma unroll
    for (int mf = 0; mf < 4; ++mf)
        #pragma unroll
        for (int nf = 0; nf < 8; ++nf) acc[mf][nf] = (f32x4v)0.f;

    const int lane = tid & 63;
    const int wid  = tid >> 6;
    const int wr   = wid >> 1;
    const int wc   = wid & 1;
    const int frow = lane & 15;
    const int fk   = (lane >> 4) * 8;

    ra[0] = *(const bf16x8*)(aptr);
    ra[1] = *(const bf16x8*)(aptr + 8);
    #pragma unroll
    for (int i = 0; i < 4; ++i) { rbA[i] = *(const f32x4v*)(bptrA + i * 4); rbB[i] = *(const f32x4v*)(bptrB + i * 4); }

    const int KT = I_DIM / BK;
    for (int kt = 0; kt < KT; ++kt) {
        __syncthreads();
        *(bf16x8*)&sA[srow][shalf * 16]           = ra[0];
        *(bf16x8*)&sA[srow][shalf * 16 + 8]       = ra[1];
        *(bf16x8*)&sB[srow][shalf * 16]           = pack8(rbA[0], rbA[1]);
        *(bf16x8*)&sB[srow][shalf * 16 + 8]       = pack8(rbA[2], rbA[3]);
        *(bf16x8*)&sB[srow + 128][shalf * 16]     = pack8(rbB[0], rbB[1]);
        *(bf16x8*)&sB[srow + 128][shalf * 16 + 8] = pack8(rbB[2], rbB[3]);
        __syncthreads();

        if (kt + 1 < KT) {
            const int k = (kt + 1) * BK;
            ra[0] = *(const bf16x8*)(aptr + k);
            ra[1] = *(const bf16x8*)(aptr + k + 8);
            #pragma unroll
            for (int i = 0; i < 4; ++i) { rbA[i] = *(const f32x4v*)(bptrA + k + i * 4); rbB[i] = *(const f32x4v*)(bptrB + k + i * 4); }
        }

        bf16x8 af[4];
        #pragma unroll
        for (int mf = 0; mf < 4; ++mf)
            af[mf] = *(const bf16x8*)&sA[wr * 64 + mf * 16 + frow][fk];
        #pragma unroll
        for (int nf = 0; nf < 8; ++nf) {
            bf16x8 bfv = *(const bf16x8*)&sB[wc * 128 + nf * 16 + frow][fk];
            #pragma unroll
            for (int mf = 0; mf < 4; ++mf)
                acc[mf][nf] = __builtin_amdgcn_mfma_f32_16x16x32_bf16(af[mf], bfv, acc[mf][nf], 0, 0, 0);
        }
    }

    const int r4 = (lane >> 4) * 4;
    #pragma unroll
    for (int mf = 0; mf < 4; ++mf)
        #pragma unroll
        for (int nf = 0; nf < 8; ++nf)
            #pragma unroll
            for (int j = 0; j < 4; ++j) {
                int rr = wr * 64 + mf * 16 + r4 + j;
                if (rr < rows) {
                    int col = n0 + wc * 128 + nf * 16 + (lane & 15);
                    atomicAdd(out + (size_t)sTok[rr] * H_DIM + col, acc[mf][nf][j]);
                }
            }
}

// ---------------- launch ----------------
extern "C" void kernel_launch(void* const* d_in, const int* in_sizes, int n_in,
                              void* d_out, int out_size, void* d_ws, size_t ws_size,
                              hipStream_t stream)
{
    (void)in_sizes; (void)n_in;
    const float* X     = (const float*)d_in[0];
    const float* topw  = (const float*)d_in[1];
    const int*   topid = (const int*)d_in[2];
    const float* Wi0   = (const float*)d_in[3];
    const float* Wi1   = (const float*)d_in[4];
    const float* Wo    = (const float*)d_in[5];
    float* out = (float*)d_out;

    char* ws = (char*)d_ws;
    int*   pair_token  = (int*)ws;
    float* pair_w      = (float*)(ws + NPAIR * 4);
    int*   tile_expert = (int*)(ws + NPAIR * 8);
    int*   tile_row0   = tile_expert + MAXT;
    int*   tile_rows   = tile_row0 + MAXT;
    int*   t1_expert   = tile_rows + MAXT;
    int*   t1_row0     = t1_expert + MAXT1;
    int*   t1_rows     = t1_row0 + MAXT1;

    route_kernel<<<1, 256, 0, stream>>>(topid, topw, pair_token, pair_w,
                                        tile_expert, tile_row0, tile_rows,
                                        t1_expert, t1_row0, t1_rows);

    if (ws_size >= NEED_NEW) {
        short* Ht  = (short*)(ws + HT_OFF);
        short* Wot = (short*)(ws + W0_OFF);
        short* At  = (short*)(ws + AT_OFF);

        hipMemsetAsync(d_out, 0, (size_t)out_size * sizeof(float), stream);

        aprep_kernel<<<2560, 256, 0, stream>>>(X, pair_token, t1_row0, t1_rows, At);

        gemm1b_kernel<<<MAXT1 * 16, 512, 0, stream>>>(
            At, Wi0, Wi1, pair_w, t1_expert, t1_row0, t1_rows, Ht);

        woprep_kernel<<<4096, 256, 0, stream>>>(Wo, Wot);

        gemm2b_kernel<<<MAXT1 * 16, 512, 0, stream>>>(
            Ht, Wot, pair_token, t1_expert, t1_row0, t1_rows, out);
    } else {
        short* Hbuf = (short*)(ws + (1 << 20));
        short* Xbf  = (short*)d_out;

        cvt_kernel<<<T_TOK * H_DIM / (256 * 8), 256, 0, stream>>>(X, Xbf);

        gemm1_kernel<<<dim3(MAXT1, I_DIM / BN1), 512, 0, stream>>>(
            Xbf, Wi0, Wi1, pair_token, pair_w, t1_expert, t1_row0, t1_rows, Hbuf);

        hipMemsetAsync(d_out, 0, (size_t)out_size * sizeof(float), stream);

        gemm2_kernel<<<dim3(MAXT, H_DIM / 256), 256, 0, stream>>>(
            Hbuf, Wo, pair_token, tile_expert, tile_row0, tile_rows, out);
    }
}